// Round 1
// baseline (3552.084 us; speedup 1.0000x reference)
//
#include <hip/hip_runtime.h>
#include <hip/hip_bf16.h>

#define NODES_H 128
#define HBITS 7   // 128 = 1<<7

// ---------------------------------------------------------------------------
// degree / normalization
// ---------------------------------------------------------------------------
__global__ void deg_init_k(float* __restrict__ deg, int N) {
    int i = blockIdx.x * blockDim.x + threadIdx.x;
    if (i < N) deg[i] = 1.0f;  // self-loop
}

__global__ void deg_count_k(const int* __restrict__ dst, float* __restrict__ deg, int E) {
    int e = blockIdx.x * blockDim.x + threadIdx.x;
    if (e < E) atomicAdd(&deg[dst[e]], 1.0f);
}

__global__ void deg_rsqrt_k(float* __restrict__ deg, int N) {
    int i = blockIdx.x * blockDim.x + threadIdx.x;
    if (i < N) deg[i] = rsqrtf(deg[i]);  // deg >= 1 always (self-loops)
}

// ---------------------------------------------------------------------------
// h init: broadcast hidden_c (128 floats) to all nodes
// ---------------------------------------------------------------------------
__global__ void h_init_k(const float* __restrict__ hc, float* __restrict__ h, int total) {
    int i = blockIdx.x * blockDim.x + threadIdx.x;
    if (i < total) h[i] = hc[i & (NODES_H - 1)];
}

// ---------------------------------------------------------------------------
// Generic tiled fp32 GEMM: C[M,N] = op(A)[M,K] @ W + bias
//   WT=false: W is [K,N] row-major.  WT=true: W is [N,K] row-major (W^T access).
//   RELU_A: apply relu to A elements on load.
// BM=BN=64, BK=16, 256 threads, 4x4 micro-tile per thread.
// Requires N % 64 == 0, K % 16 == 0 (true here: N in {128,384}, K in {16,128}).
// ---------------------------------------------------------------------------
#define BM 64
#define BN 64
#define BK 16

template <bool WT, bool RELU_A>
__global__ __launch_bounds__(256) void gemm_k(const float* __restrict__ A,
                                              const float* __restrict__ W,
                                              const float* __restrict__ bias,
                                              float* __restrict__ C,
                                              int M, int K, int N) {
    __shared__ float As[BK][BM + 1];
    __shared__ float Ws[BK][BN + 1];

    const int gn = N / BN;
    const int bx = blockIdx.x % gn;
    const int by = blockIdx.x / gn;
    const int tid = threadIdx.x;
    const int tx = tid & 15;
    const int ty = tid >> 4;
    const int row0 = by * BM;
    const int col0 = bx * BN;

    float acc[4][4] = {};

    for (int k0 = 0; k0 < K; k0 += BK) {
        // load A tile: 64 rows x 16 k  (1024 elems / 256 threads = 4 each)
#pragma unroll
        for (int i = 0; i < 4; ++i) {
            int idx = tid + i * 256;
            int r = idx >> 4, k = idx & 15;
            int gr = row0 + r;
            float v = (gr < M) ? A[(size_t)gr * K + k0 + k] : 0.0f;
            if (RELU_A) v = fmaxf(v, 0.0f);
            As[k][r] = v;
        }
        // load W tile
#pragma unroll
        for (int i = 0; i < 4; ++i) {
            int idx = tid + i * 256;
            if (!WT) {
                int k = idx >> 6, n = idx & 63;
                Ws[k][n] = W[(size_t)(k0 + k) * N + col0 + n];
            } else {
                int n = idx >> 4, k = idx & 15;
                Ws[k][n] = W[(size_t)(col0 + n) * K + k0 + k];
            }
        }
        __syncthreads();

#pragma unroll
        for (int kk = 0; kk < BK; ++kk) {
            float a[4], w[4];
#pragma unroll
            for (int i = 0; i < 4; ++i) a[i] = As[kk][ty * 4 + i];
#pragma unroll
            for (int j = 0; j < 4; ++j) w[j] = Ws[kk][tx * 4 + j];
#pragma unroll
            for (int i = 0; i < 4; ++i)
#pragma unroll
                for (int j = 0; j < 4; ++j) acc[i][j] += a[i] * w[j];
        }
        __syncthreads();
    }

#pragma unroll
    for (int i = 0; i < 4; ++i) {
        int gr = row0 + ty * 4 + i;
        if (gr >= M) continue;
#pragma unroll
        for (int j = 0; j < 4; ++j) {
            int gc = col0 + tx * 4 + j;
            float v = acc[i][j];
            if (bias) v += bias[gc];
            C[(size_t)gr * N + gc] = v;
        }
    }
}

// ---------------------------------------------------------------------------
// GCN aggregation: out[i][:] = HW[i][:]*dis[i]^2 + b[:]   (self-loop + bias)
// then atomic scatter over edges: out[dst] += HW[src]*dis[src]*dis[dst]
// (relu deferred to the consumer GEMM's A-load)
// ---------------------------------------------------------------------------
__global__ void gcn_init_k(const float* __restrict__ HW, const float* __restrict__ dis,
                           const float* __restrict__ bias, float* __restrict__ out, int total) {
    int idx = blockIdx.x * blockDim.x + threadIdx.x;
    if (idx >= total) return;
    int node = idx >> HBITS;
    int c = idx & (NODES_H - 1);
    float d = dis[node];
    out[idx] = HW[idx] * d * d + bias[c];
}

__global__ void gcn_scatter_k(const float* __restrict__ HW, const float* __restrict__ dis,
                              const int* __restrict__ src, const int* __restrict__ dst,
                              float* __restrict__ out, int E) {
    long long gid = (long long)blockIdx.x * blockDim.x + threadIdx.x;
    long long e = gid >> HBITS;
    if (e >= E) return;
    int c = (int)(gid & (NODES_H - 1));
    int s = src[e], d = dst[e];
    float w = dis[s] * dis[d];
    atomicAdd(&out[(size_t)d * NODES_H + c], HW[(size_t)s * NODES_H + c] * w);
}

// ---------------------------------------------------------------------------
// GRU finalize: h_new = (1-z)*n + z*h  from gi [N,384], gh [N,384], h [N,128]
// ---------------------------------------------------------------------------
__global__ void gru_finalize_k(const float* __restrict__ gi, const float* __restrict__ gh,
                               const float* __restrict__ h, float* __restrict__ hn, int total) {
    int idx = blockIdx.x * blockDim.x + threadIdx.x;
    if (idx >= total) return;
    int node = idx >> HBITS;
    int j = idx & (NODES_H - 1);
    size_t b = (size_t)node * 384;
    float ir = gi[b + j], iz = gi[b + 128 + j], in_ = gi[b + 256 + j];
    float hr = gh[b + j], hz = gh[b + 128 + j], hn_ = gh[b + 256 + j];
    float r = 1.0f / (1.0f + expf(-(ir + hr)));
    float z = 1.0f / (1.0f + expf(-(iz + hz)));
    float n = tanhf(in_ + r * hn_);
    hn[idx] = (1.0f - z) * n + z * h[idx];
}

// ---------------------------------------------------------------------------
// Output head: logits = h @ out_W + out_b (OUT=5), softmax, write fp32.
// One wave (64 lanes) per node; each lane holds h[lane], h[lane+64].
// ---------------------------------------------------------------------------
#define OUT_DIM 5
__global__ void out_softmax_k(const float* __restrict__ h, const float* __restrict__ Wo,
                              const float* __restrict__ bo, float* __restrict__ out, int N) {
    int gtid = blockIdx.x * blockDim.x + threadIdx.x;
    int node = gtid >> 6;
    int lane = threadIdx.x & 63;
    if (node >= N) return;
    const float* hr = h + (size_t)node * NODES_H;
    float h0 = hr[lane];
    float h1 = hr[lane + 64];
    float acc[OUT_DIM];
#pragma unroll
    for (int o = 0; o < OUT_DIM; ++o)
        acc[o] = h0 * Wo[lane * OUT_DIM + o] + h1 * Wo[(lane + 64) * OUT_DIM + o];
#pragma unroll
    for (int off = 32; off >= 1; off >>= 1) {
#pragma unroll
        for (int o = 0; o < OUT_DIM; ++o) acc[o] += __shfl_down(acc[o], off, 64);
    }
    if (lane == 0) {
        float v[OUT_DIM], m = -1e30f;
#pragma unroll
        for (int o = 0; o < OUT_DIM; ++o) { v[o] = acc[o] + bo[o]; m = fmaxf(m, v[o]); }
        float s = 0.0f;
#pragma unroll
        for (int o = 0; o < OUT_DIM; ++o) { v[o] = expf(v[o] - m); s += v[o]; }
        float inv = 1.0f / s;
#pragma unroll
        for (int o = 0; o < OUT_DIM; ++o) out[(size_t)node * OUT_DIM + o] = v[o] * inv;
    }
}

// ---------------------------------------------------------------------------
// launch
// ---------------------------------------------------------------------------
static inline int cdiv(long long a, long long b) { return (int)((a + b - 1) / b); }

extern "C" void kernel_launch(void* const* d_in, const int* in_sizes, int n_in,
                              void* d_out, int out_size, void* d_ws, size_t ws_size,
                              hipStream_t stream) {
    const float* x       = (const float*)d_in[0];
    const int*   eidx    = (const int*)d_in[1];
    const float* proj_W  = (const float*)d_in[2];
    const float* proj_b  = (const float*)d_in[3];
    const float* conv1_W = (const float*)d_in[4];
    const float* conv1_b = (const float*)d_in[5];
    const float* conv2_W = (const float*)d_in[6];
    const float* conv2_b = (const float*)d_in[7];
    const float* hidden_c= (const float*)d_in[8];
    const float* gru_Wih = (const float*)d_in[9];
    const float* gru_Whh = (const float*)d_in[10];
    const float* gru_bih = (const float*)d_in[11];
    const float* gru_bhh = (const float*)d_in[12];
    const float* out_W   = (const float*)d_in[13];
    const float* out_b   = (const float*)d_in[14];
    float* out = (float*)d_out;

    const int F = 16, H = 128, G3 = 384;
    const int N = in_sizes[0] / F;
    const int E = in_sizes[1] / 2;
    const int* src = eidx;
    const int* dst = eidx + E;

    // workspace layout (floats): dis | h0 | h1 | A | G1 | G2(alias HW)
    float* ws   = (float*)d_ws;
    float* dis  = ws;                       // N
    float* h0   = dis + N;                  // N*H
    float* h1   = h0 + (size_t)N * H;       // N*H
    float* Abuf = h1 + (size_t)N * H;       // N*H
    float* G1   = Abuf + (size_t)N * H;     // N*G3
    float* G2   = G1 + (size_t)N * G3;      // N*G3  (also used as HW [N*H])
    float* HW   = G2;

    const int TPB = 256;
    const int totNH = N * H;

    // --- normalization ---
    deg_init_k<<<cdiv(N, TPB), TPB, 0, stream>>>(dis, N);
    deg_count_k<<<cdiv(E, TPB), TPB, 0, stream>>>(dst, dis, E);
    deg_rsqrt_k<<<cdiv(N, TPB), TPB, 0, stream>>>(dis, N);

    // --- h = broadcast(hidden_c) ---
    h_init_k<<<cdiv(totNH, TPB), TPB, 0, stream>>>(hidden_c, h0, totNH);

    float* h_cur = h0;
    float* h_nxt = h1;

    const int gm = cdiv(N, BM);
    dim3 gridH(gm * (H / BN));    // N-dim 128
    dim3 gridG(gm * (G3 / BN));   // N-dim 384

    // --- proj: A = x @ proj_W + proj_b ---
    gemm_k<false, false><<<gridH, TPB, 0, stream>>>(x, proj_W, proj_b, Abuf, N, F, H);

    // --- GRU step 0 (input = A, no relu) ---
    gemm_k<true, false><<<gridG, TPB, 0, stream>>>(Abuf, gru_Wih, gru_bih, G1, N, H, G3);
    gemm_k<true, false><<<gridG, TPB, 0, stream>>>(h_cur, gru_Whh, gru_bhh, G2, N, H, G3);
    gru_finalize_k<<<cdiv(totNH, TPB), TPB, 0, stream>>>(G1, G2, h_cur, h_nxt, totNH);
    { float* t = h_cur; h_cur = h_nxt; h_nxt = t; }

    const long long scatTot = (long long)E * H;
    const int scatBlocks = cdiv(scatTot, TPB);

    for (int it = 0; it < 3; ++it) {
        // gcn1: HW = h @ conv1_W ; A = scatter(HW) + b1
        gemm_k<false, false><<<gridH, TPB, 0, stream>>>(h_cur, conv1_W, nullptr, HW, N, H, H);
        gcn_init_k<<<cdiv(totNH, TPB), TPB, 0, stream>>>(HW, dis, conv1_b, Abuf, totNH);
        gcn_scatter_k<<<scatBlocks, TPB, 0, stream>>>(HW, dis, src, dst, Abuf, E);
        // gcn2: HW = relu(A) @ conv2_W ; A = scatter(HW) + b2
        gemm_k<false, true><<<gridH, TPB, 0, stream>>>(Abuf, conv2_W, nullptr, HW, N, H, H);
        gcn_init_k<<<cdiv(totNH, TPB), TPB, 0, stream>>>(HW, dis, conv2_b, Abuf, totNH);
        gcn_scatter_k<<<scatBlocks, TPB, 0, stream>>>(HW, dis, src, dst, Abuf, E);
        // GRU (input = relu(A))
        gemm_k<true, true><<<gridG, TPB, 0, stream>>>(Abuf, gru_Wih, gru_bih, G1, N, H, G3);
        gemm_k<true, false><<<gridG, TPB, 0, stream>>>(h_cur, gru_Whh, gru_bhh, G2, N, H, G3);
        gru_finalize_k<<<cdiv(totNH, TPB), TPB, 0, stream>>>(G1, G2, h_cur, h_nxt, totNH);
        { float* t = h_cur; h_cur = h_nxt; h_nxt = t; }
    }

    // --- output head ---
    out_softmax_k<<<cdiv((long long)N * 64, TPB), TPB, 0, stream>>>(h_cur, out_W, out_b, out, N);
}

// Round 2
// 1971.412 us; speedup vs baseline: 1.8018x; 1.8018x over previous
//
#include <hip/hip_runtime.h>
#include <hip/hip_bf16.h>

#define NODES_H 128
#define HBITS 7   // 128 = 1<<7

// ---------------------------------------------------------------------------
// CSR build: histogram -> 2-level exclusive scan -> reorder (+ edge weights)
// ---------------------------------------------------------------------------
__global__ void zero_cnt_k(int* __restrict__ cnt, int N) {
    int i = blockIdx.x * blockDim.x + threadIdx.x;
    if (i < N) cnt[i] = 0;
}

__global__ void count_k(const int* __restrict__ dst, int* __restrict__ cnt, int E) {
    int e = blockIdx.x * blockDim.x + threadIdx.x;
    if (e < E) atomicAdd(&cnt[dst[e]], 1);
}

// per-block inclusive->exclusive scan; writes within-block exclusive prefix to
// rowptr[i], block total to bsum[blockIdx.x]
__global__ __launch_bounds__(256) void scan1_k(const int* __restrict__ cnt,
                                               int* __restrict__ rowptr,
                                               int* __restrict__ bsum, int N) {
    __shared__ int buf[256];
    int tid = threadIdx.x;
    int i = blockIdx.x * 256 + tid;
    int v = (i < N) ? cnt[i] : 0;
    buf[tid] = v;
    __syncthreads();
#pragma unroll
    for (int off = 1; off < 256; off <<= 1) {
        int t = (tid >= off) ? buf[tid - off] : 0;
        __syncthreads();
        buf[tid] += t;
        __syncthreads();
    }
    if (i < N) rowptr[i] = buf[tid] - v;  // exclusive within block
    if (tid == 255) bsum[blockIdx.x] = buf[255];
}

// exclusive scan of block sums (nb <= 256), in place
__global__ __launch_bounds__(256) void scan2_k(int* __restrict__ bsum, int nb) {
    __shared__ int buf[256];
    int tid = threadIdx.x;
    int v = (tid < nb) ? bsum[tid] : 0;
    buf[tid] = v;
    __syncthreads();
#pragma unroll
    for (int off = 1; off < 256; off <<= 1) {
        int t = (tid >= off) ? buf[tid - off] : 0;
        __syncthreads();
        buf[tid] += t;
        __syncthreads();
    }
    if (tid < nb) bsum[tid] = buf[tid] - v;
}

// finalize rowptr (+ block offset), init write cursors, compute dis = deg^-1/2
__global__ void scan3_k(int* __restrict__ rowptr, const int* __restrict__ bsum,
                        const int* __restrict__ cnt, int* __restrict__ pos,
                        float* __restrict__ dis, int N, int E) {
    int i = blockIdx.x * blockDim.x + threadIdx.x;
    if (i < N) {
        int v = rowptr[i] + bsum[blockIdx.x * blockDim.x / 256 + (threadIdx.x >= 0 ? 0 : 0)];
        // NOTE: blockDim.x == 256 so block index maps 1:1 to scan1 blocks
        v = rowptr[i] + bsum[blockIdx.x];
        rowptr[i] = v;
        pos[i] = v;
        dis[i] = rsqrtf((float)(cnt[i] + 1));  // +1 self-loop
    }
    if (i == 0) rowptr[N] = E;
}

__global__ void reorder_k(const int* __restrict__ src, const int* __restrict__ dst,
                          const float* __restrict__ dis, int* __restrict__ pos,
                          int* __restrict__ csr_src, float* __restrict__ csr_w, int E) {
    int e = blockIdx.x * blockDim.x + threadIdx.x;
    if (e >= E) return;
    int s = src[e], d = dst[e];
    int p = atomicAdd(&pos[d], 1);
    csr_src[p] = s;
    csr_w[p] = dis[s] * dis[d];
}

// ---------------------------------------------------------------------------
// h init: broadcast hidden_c (128 floats) to all nodes
// ---------------------------------------------------------------------------
__global__ void h_init_k(const float* __restrict__ hc, float* __restrict__ h, int total) {
    int i = blockIdx.x * blockDim.x + threadIdx.x;
    if (i < total) h[i] = hc[i & (NODES_H - 1)];
}

// ---------------------------------------------------------------------------
// Generic tiled fp32 GEMM: C[M,N] = op(A)[M,K] @ W + bias
//   WT=false: W is [K,N] row-major.  WT=true: W is [N,K] row-major (W^T access).
//   RELU_A: apply relu to A elements on load.
// ---------------------------------------------------------------------------
#define BM 64
#define BN 64
#define BK 16

template <bool WT, bool RELU_A>
__global__ __launch_bounds__(256) void gemm_k(const float* __restrict__ A,
                                              const float* __restrict__ W,
                                              const float* __restrict__ bias,
                                              float* __restrict__ C,
                                              int M, int K, int N) {
    __shared__ float As[BK][BM + 1];
    __shared__ float Ws[BK][BN + 1];

    const int gn = N / BN;
    const int bx = blockIdx.x % gn;
    const int by = blockIdx.x / gn;
    const int tid = threadIdx.x;
    const int tx = tid & 15;
    const int ty = tid >> 4;
    const int row0 = by * BM;
    const int col0 = bx * BN;

    float acc[4][4] = {};

    for (int k0 = 0; k0 < K; k0 += BK) {
#pragma unroll
        for (int i = 0; i < 4; ++i) {
            int idx = tid + i * 256;
            int r = idx >> 4, k = idx & 15;
            int gr = row0 + r;
            float v = (gr < M) ? A[(size_t)gr * K + k0 + k] : 0.0f;
            if (RELU_A) v = fmaxf(v, 0.0f);
            As[k][r] = v;
        }
#pragma unroll
        for (int i = 0; i < 4; ++i) {
            int idx = tid + i * 256;
            if (!WT) {
                int k = idx >> 6, n = idx & 63;
                Ws[k][n] = W[(size_t)(k0 + k) * N + col0 + n];
            } else {
                int n = idx >> 4, k = idx & 15;
                Ws[k][n] = W[(size_t)(col0 + n) * K + k0 + k];
            }
        }
        __syncthreads();

#pragma unroll
        for (int kk = 0; kk < BK; ++kk) {
            float a[4], w[4];
#pragma unroll
            for (int i = 0; i < 4; ++i) a[i] = As[kk][ty * 4 + i];
#pragma unroll
            for (int j = 0; j < 4; ++j) w[j] = Ws[kk][tx * 4 + j];
#pragma unroll
            for (int i = 0; i < 4; ++i)
#pragma unroll
                for (int j = 0; j < 4; ++j) acc[i][j] += a[i] * w[j];
        }
        __syncthreads();
    }

#pragma unroll
    for (int i = 0; i < 4; ++i) {
        int gr = row0 + ty * 4 + i;
        if (gr >= M) continue;
#pragma unroll
        for (int j = 0; j < 4; ++j) {
            int gc = col0 + tx * 4 + j;
            float v = acc[i][j];
            if (bias) v += bias[gc];
            C[(size_t)gr * N + gc] = v;
        }
    }
}

// ---------------------------------------------------------------------------
// GCN aggregation, pull style: one wave per destination node.
// out[d][:] = HW[d][:]*dis[d]^2 + bias + sum_e w[e]*HW[csr_src[e]][:]
// lane i owns columns {2i, 2i+1} via float2 (wave covers all 128, 512B/req).
// ---------------------------------------------------------------------------
__global__ __launch_bounds__(256) void gcn_gather_k(const float* __restrict__ HW,
                                                    const float* __restrict__ dis,
                                                    const int* __restrict__ rowptr,
                                                    const int* __restrict__ csr_src,
                                                    const float* __restrict__ csr_w,
                                                    const float* __restrict__ bias,
                                                    float* __restrict__ out, int N) {
    int node = (blockIdx.x * 256 + threadIdx.x) >> 6;
    int lane = threadIdx.x & 63;
    if (node >= N) return;
    float dd = dis[node];
    float2 hw = *(const float2*)&HW[((size_t)node << HBITS) + lane * 2];
    float2 b2 = *(const float2*)&bias[lane * 2];
    float accx = hw.x * dd * dd + b2.x;
    float accy = hw.y * dd * dd + b2.y;
    int beg = rowptr[node], end = rowptr[node + 1];
    for (int e = beg; e < end; ++e) {
        int s = csr_src[e];
        float w = csr_w[e];
        float2 v = *(const float2*)&HW[((size_t)s << HBITS) + lane * 2];
        accx += v.x * w;
        accy += v.y * w;
    }
    float2 r;
    r.x = accx;
    r.y = accy;
    *(float2*)&out[((size_t)node << HBITS) + lane * 2] = r;
}

// ---------------------------------------------------------------------------
// GRU finalize: h_new = (1-z)*n + z*h  from gi [N,384], gh [N,384], h [N,128]
// ---------------------------------------------------------------------------
__global__ void gru_finalize_k(const float* __restrict__ gi, const float* __restrict__ gh,
                               const float* __restrict__ h, float* __restrict__ hn, int total) {
    int idx = blockIdx.x * blockDim.x + threadIdx.x;
    if (idx >= total) return;
    int node = idx >> HBITS;
    int j = idx & (NODES_H - 1);
    size_t b = (size_t)node * 384;
    float ir = gi[b + j], iz = gi[b + 128 + j], in_ = gi[b + 256 + j];
    float hr = gh[b + j], hz = gh[b + 128 + j], hn_ = gh[b + 256 + j];
    float r = 1.0f / (1.0f + expf(-(ir + hr)));
    float z = 1.0f / (1.0f + expf(-(iz + hz)));
    float n = tanhf(in_ + r * hn_);
    hn[idx] = (1.0f - z) * n + z * h[idx];
}

// ---------------------------------------------------------------------------
// Output head: logits = h @ out_W + out_b (OUT=5), softmax.
// ---------------------------------------------------------------------------
#define OUT_DIM 5
__global__ void out_softmax_k(const float* __restrict__ h, const float* __restrict__ Wo,
                              const float* __restrict__ bo, float* __restrict__ out, int N) {
    int gtid = blockIdx.x * blockDim.x + threadIdx.x;
    int node = gtid >> 6;
    int lane = threadIdx.x & 63;
    if (node >= N) return;
    const float* hr = h + ((size_t)node << HBITS);
    float h0 = hr[lane];
    float h1 = hr[lane + 64];
    float acc[OUT_DIM];
#pragma unroll
    for (int o = 0; o < OUT_DIM; ++o)
        acc[o] = h0 * Wo[lane * OUT_DIM + o] + h1 * Wo[(lane + 64) * OUT_DIM + o];
#pragma unroll
    for (int off = 32; off >= 1; off >>= 1) {
#pragma unroll
        for (int o = 0; o < OUT_DIM; ++o) acc[o] += __shfl_down(acc[o], off, 64);
    }
    if (lane == 0) {
        float v[OUT_DIM], m = -1e30f;
#pragma unroll
        for (int o = 0; o < OUT_DIM; ++o) { v[o] = acc[o] + bo[o]; m = fmaxf(m, v[o]); }
        float s = 0.0f;
#pragma unroll
        for (int o = 0; o < OUT_DIM; ++o) { v[o] = expf(v[o] - m); s += v[o]; }
        float inv = 1.0f / s;
#pragma unroll
        for (int o = 0; o < OUT_DIM; ++o) out[(size_t)node * OUT_DIM + o] = v[o] * inv;
    }
}

// ---------------------------------------------------------------------------
// launch
// ---------------------------------------------------------------------------
static inline int cdiv(long long a, long long b) { return (int)((a + b - 1) / b); }

extern "C" void kernel_launch(void* const* d_in, const int* in_sizes, int n_in,
                              void* d_out, int out_size, void* d_ws, size_t ws_size,
                              hipStream_t stream) {
    const float* x       = (const float*)d_in[0];
    const int*   eidx    = (const int*)d_in[1];
    const float* proj_W  = (const float*)d_in[2];
    const float* proj_b  = (const float*)d_in[3];
    const float* conv1_W = (const float*)d_in[4];
    const float* conv1_b = (const float*)d_in[5];
    const float* conv2_W = (const float*)d_in[6];
    const float* conv2_b = (const float*)d_in[7];
    const float* hidden_c= (const float*)d_in[8];
    const float* gru_Wih = (const float*)d_in[9];
    const float* gru_Whh = (const float*)d_in[10];
    const float* gru_bih = (const float*)d_in[11];
    const float* gru_bhh = (const float*)d_in[12];
    const float* out_W   = (const float*)d_in[13];
    const float* out_b   = (const float*)d_in[14];
    float* out = (float*)d_out;

    const int F = 16, H = 128, G3 = 384;
    const int N = in_sizes[0] / F;
    const int E = in_sizes[1] / 2;
    const int* src = eidx;
    const int* dst = eidx + E;

    const int TPB = 256;
    const int nScanBlocks = cdiv(N, 256);

    // workspace layout
    char* wp = (char*)d_ws;
    int*   cnt     = (int*)wp;              wp += (size_t)N * 4;
    int*   rowptr  = (int*)wp;              wp += (size_t)(N + 1) * 4;
    int*   pos     = (int*)wp;              wp += (size_t)N * 4;
    int*   bsum    = (int*)wp;              wp += 256 * 4;
    int*   csr_src = (int*)wp;              wp += (size_t)E * 4;
    float* csr_w   = (float*)wp;            wp += (size_t)E * 4;
    float* dis     = (float*)wp;            wp += (size_t)N * 4;
    float* h0      = (float*)wp;            wp += (size_t)N * H * 4;
    float* h1      = (float*)wp;            wp += (size_t)N * H * 4;
    float* Abuf    = (float*)wp;            wp += (size_t)N * H * 4;
    float* G1      = (float*)wp;            wp += (size_t)N * G3 * 4;
    float* G2      = (float*)wp;            wp += (size_t)N * G3 * 4;
    float* HW      = G2;  // alias: HW [N*H] only live outside GRU GEMMs

    const int totNH = N * H;

    // --- CSR build + normalization ---
    zero_cnt_k<<<cdiv(N, TPB), TPB, 0, stream>>>(cnt, N);
    count_k<<<cdiv(E, TPB), TPB, 0, stream>>>(dst, cnt, E);
    scan1_k<<<nScanBlocks, 256, 0, stream>>>(cnt, rowptr, bsum, N);
    scan2_k<<<1, 256, 0, stream>>>(bsum, nScanBlocks);
    scan3_k<<<nScanBlocks, 256, 0, stream>>>(rowptr, bsum, cnt, pos, dis, N, E);
    reorder_k<<<cdiv(E, TPB), TPB, 0, stream>>>(src, dst, dis, pos, csr_src, csr_w, E);

    // --- h = broadcast(hidden_c) ---
    h_init_k<<<cdiv(totNH, TPB), TPB, 0, stream>>>(hidden_c, h0, totNH);

    float* h_cur = h0;
    float* h_nxt = h1;

    const int gm = cdiv(N, BM);
    dim3 gridH(gm * (H / BN));
    dim3 gridG(gm * (G3 / BN));
    const int gatherBlocks = cdiv((long long)N * 64, TPB);

    // --- proj: A = x @ proj_W + proj_b ---
    gemm_k<false, false><<<gridH, TPB, 0, stream>>>(x, proj_W, proj_b, Abuf, N, F, H);

    // --- GRU step 0 ---
    gemm_k<true, false><<<gridG, TPB, 0, stream>>>(Abuf, gru_Wih, gru_bih, G1, N, H, G3);
    gemm_k<true, false><<<gridG, TPB, 0, stream>>>(h_cur, gru_Whh, gru_bhh, G2, N, H, G3);
    gru_finalize_k<<<cdiv(totNH, TPB), TPB, 0, stream>>>(G1, G2, h_cur, h_nxt, totNH);
    { float* t = h_cur; h_cur = h_nxt; h_nxt = t; }

    for (int it = 0; it < 3; ++it) {
        // gcn1: HW = h @ conv1_W ; A = gather(HW) + b1
        gemm_k<false, false><<<gridH, TPB, 0, stream>>>(h_cur, conv1_W, nullptr, HW, N, H, H);
        gcn_gather_k<<<gatherBlocks, TPB, 0, stream>>>(HW, dis, rowptr, csr_src, csr_w,
                                                       conv1_b, Abuf, N);
        // gcn2: HW = relu(A) @ conv2_W ; A = gather(HW) + b2
        gemm_k<false, true><<<gridH, TPB, 0, stream>>>(Abuf, conv2_W, nullptr, HW, N, H, H);
        gcn_gather_k<<<gatherBlocks, TPB, 0, stream>>>(HW, dis, rowptr, csr_src, csr_w,
                                                       conv2_b, Abuf, N);
        // GRU (input = relu(A))
        gemm_k<true, true><<<gridG, TPB, 0, stream>>>(Abuf, gru_Wih, gru_bih, G1, N, H, G3);
        gemm_k<true, false><<<gridG, TPB, 0, stream>>>(h_cur, gru_Whh, gru_bhh, G2, N, H, G3);
        gru_finalize_k<<<cdiv(totNH, TPB), TPB, 0, stream>>>(G1, G2, h_cur, h_nxt, totNH);
        { float* t = h_cur; h_cur = h_nxt; h_nxt = t; }
    }

    // --- output head ---
    out_softmax_k<<<cdiv((long long)N * 64, TPB), TPB, 0, stream>>>(h_cur, out_W, out_b, out, N);
}

// Round 3
// 1296.740 us; speedup vs baseline: 2.7392x; 1.5203x over previous
//
#include <hip/hip_runtime.h>
#include <hip/hip_bf16.h>

#define NODES_H 128
#define HBITS 7   // 128 = 1<<7

typedef __attribute__((ext_vector_type(8))) short bf16x8;
typedef __attribute__((ext_vector_type(4))) float f32x4;

static __device__ __forceinline__ short f2bf(float f) {
    union { float f; unsigned u; } v; v.f = f;
    unsigned r = v.u + 0x7FFFu + ((v.u >> 16) & 1u);  // RNE
    return (short)(r >> 16);
}

// ---------------------------------------------------------------------------
// weight preconversion: straight fp32->bf16, and transposed (out[n][k] = in[k][n])
// ---------------------------------------------------------------------------
__global__ void cvt_bf16_k(const float* __restrict__ in, short* __restrict__ out, int n) {
    int i = blockIdx.x * blockDim.x + threadIdx.x;
    if (i < n) out[i] = f2bf(in[i]);
}

__global__ void cvt_bf16_t_k(const float* __restrict__ in, short* __restrict__ out, int K, int N) {
    int i = blockIdx.x * blockDim.x + threadIdx.x;
    if (i >= K * N) return;
    int nn = i >> HBITS;      // K==128 assumed for in's row length? no: out index
    int kk = i & (NODES_H - 1);
    // out[nn*K + kk] = in[kk*N + nn];  (K==128 here)
    out[i] = f2bf(in[kk * N + nn]);
}

// ---------------------------------------------------------------------------
// CSR build: histogram -> 2-level exclusive scan -> reorder (+ edge weights)
// ---------------------------------------------------------------------------
__global__ void zero_cnt_k(int* __restrict__ cnt, int N) {
    int i = blockIdx.x * blockDim.x + threadIdx.x;
    if (i < N) cnt[i] = 0;
}

__global__ void count_k(const int* __restrict__ dst, int* __restrict__ cnt, int E) {
    int e = blockIdx.x * blockDim.x + threadIdx.x;
    if (e < E) atomicAdd(&cnt[dst[e]], 1);
}

__global__ __launch_bounds__(256) void scan1_k(const int* __restrict__ cnt,
                                               int* __restrict__ rowptr,
                                               int* __restrict__ bsum, int N) {
    __shared__ int buf[256];
    int tid = threadIdx.x;
    int i = blockIdx.x * 256 + tid;
    int v = (i < N) ? cnt[i] : 0;
    buf[tid] = v;
    __syncthreads();
#pragma unroll
    for (int off = 1; off < 256; off <<= 1) {
        int t = (tid >= off) ? buf[tid - off] : 0;
        __syncthreads();
        buf[tid] += t;
        __syncthreads();
    }
    if (i < N) rowptr[i] = buf[tid] - v;
    if (tid == 255) bsum[blockIdx.x] = buf[255];
}

__global__ __launch_bounds__(256) void scan2_k(int* __restrict__ bsum, int nb) {
    __shared__ int buf[256];
    int tid = threadIdx.x;
    int v = (tid < nb) ? bsum[tid] : 0;
    buf[tid] = v;
    __syncthreads();
#pragma unroll
    for (int off = 1; off < 256; off <<= 1) {
        int t = (tid >= off) ? buf[tid - off] : 0;
        __syncthreads();
        buf[tid] += t;
        __syncthreads();
    }
    if (tid < nb) bsum[tid] = buf[tid] - v;
}

__global__ void scan3_k(int* __restrict__ rowptr, const int* __restrict__ bsum,
                        const int* __restrict__ cnt, int* __restrict__ pos,
                        float* __restrict__ dis, int N, int E) {
    int i = blockIdx.x * blockDim.x + threadIdx.x;
    if (i < N) {
        int v = rowptr[i] + bsum[blockIdx.x];
        rowptr[i] = v;
        pos[i] = v;
        dis[i] = rsqrtf((float)(cnt[i] + 1));
    }
    if (i == 0) rowptr[N] = E;
}

__global__ void reorder_k(const int* __restrict__ src, const int* __restrict__ dst,
                          const float* __restrict__ dis, int* __restrict__ pos,
                          int* __restrict__ csr_src, float* __restrict__ csr_w, int E) {
    int e = blockIdx.x * blockDim.x + threadIdx.x;
    if (e >= E) return;
    int s = src[e], d = dst[e];
    int p = atomicAdd(&pos[d], 1);
    csr_src[p] = s;
    csr_w[p] = dis[s] * dis[d];
}

// ---------------------------------------------------------------------------
// h init
// ---------------------------------------------------------------------------
__global__ void h_init_k(const float* __restrict__ hc, float* __restrict__ h, int total) {
    int i = blockIdx.x * blockDim.x + threadIdx.x;
    if (i < total) h[i] = hc[i & (NODES_H - 1)];
}

// ---------------------------------------------------------------------------
// fp32 tiled GEMM (kept for proj: K=16)
// ---------------------------------------------------------------------------
#define BM 64
#define BN 64
#define BK 16

template <bool WT, bool RELU_A>
__global__ __launch_bounds__(256) void gemm_k(const float* __restrict__ A,
                                              const float* __restrict__ W,
                                              const float* __restrict__ bias,
                                              float* __restrict__ C,
                                              int M, int K, int N) {
    __shared__ float As[BK][BM + 1];
    __shared__ float Ws[BK][BN + 1];

    const int gn = N / BN;
    const int bx = blockIdx.x % gn;
    const int by = blockIdx.x / gn;
    const int tid = threadIdx.x;
    const int tx = tid & 15;
    const int ty = tid >> 4;
    const int row0 = by * BM;
    const int col0 = bx * BN;

    float acc[4][4] = {};

    for (int k0 = 0; k0 < K; k0 += BK) {
#pragma unroll
        for (int i = 0; i < 4; ++i) {
            int idx = tid + i * 256;
            int r = idx >> 4, k = idx & 15;
            int gr = row0 + r;
            float v = (gr < M) ? A[(size_t)gr * K + k0 + k] : 0.0f;
            if (RELU_A) v = fmaxf(v, 0.0f);
            As[k][r] = v;
        }
#pragma unroll
        for (int i = 0; i < 4; ++i) {
            int idx = tid + i * 256;
            if (!WT) {
                int k = idx >> 6, n = idx & 63;
                Ws[k][n] = W[(size_t)(k0 + k) * N + col0 + n];
            } else {
                int n = idx >> 4, k = idx & 15;
                Ws[k][n] = W[(size_t)(col0 + n) * K + k0 + k];
            }
        }
        __syncthreads();

#pragma unroll
        for (int kk = 0; kk < BK; ++kk) {
            float a[4], w[4];
#pragma unroll
            for (int i = 0; i < 4; ++i) a[i] = As[kk][ty * 4 + i];
#pragma unroll
            for (int j = 0; j < 4; ++j) w[j] = Ws[kk][tx * 4 + j];
#pragma unroll
            for (int i = 0; i < 4; ++i)
#pragma unroll
                for (int j = 0; j < 4; ++j) acc[i][j] += a[i] * w[j];
        }
        __syncthreads();
    }

#pragma unroll
    for (int i = 0; i < 4; ++i) {
        int gr = row0 + ty * 4 + i;
        if (gr >= M) continue;
#pragma unroll
        for (int j = 0; j < 4; ++j) {
            int gc = col0 + tx * 4 + j;
            float v = acc[i][j];
            if (bias) v += bias[gc];
            C[(size_t)gr * N + gc] = v;
        }
    }
}

// ---------------------------------------------------------------------------
// bf16 MFMA GEMM: C[M,N] = relu?(A fp32 [M,128]) @ Wt^T + bias
//   Wt is bf16 [N][128] (k-contiguous).  K fixed at 128 (whole K in LDS).
// Block: 128x128 tile, 256 threads (4 waves, each 64x64 via 4x4 frags of
// mfma_f32_16x16x32_bf16). LDS XOR-swizzle (chunk ^= row&7) on both tiles.
// ---------------------------------------------------------------------------
template <bool RELU_A, bool HAS_BIAS>
__global__ __launch_bounds__(256) void gemm_mfma_k(const float* __restrict__ A,
                                                   const short* __restrict__ Wt,
                                                   const float* __restrict__ bias,
                                                   float* __restrict__ C,
                                                   int M, int N) {
    __shared__ short As[128 * 128];
    __shared__ short Bs[128 * 128];

    const int gn = N >> 7;
    const int bx = blockIdx.x % gn;
    const int by = blockIdx.x / gn;
    const int row0 = by << 7, col0 = bx << 7;
    const int tid = threadIdx.x;

    // --- stage A: fp32 -> bf16, swizzled.  2048 chunks of 8 elems ---
#pragma unroll
    for (int i = 0; i < 8; ++i) {
        int chunk = tid + (i << 8);
        int r = chunk >> 4, c = chunk & 15;
        int gr = row0 + r;
        float f[8];
        if (gr < M) {
            const float4 v0 = *(const float4*)(A + (((size_t)gr) << 7) + (c << 3));
            const float4 v1 = *(const float4*)(A + (((size_t)gr) << 7) + (c << 3) + 4);
            f[0] = v0.x; f[1] = v0.y; f[2] = v0.z; f[3] = v0.w;
            f[4] = v1.x; f[5] = v1.y; f[6] = v1.z; f[7] = v1.w;
        } else {
#pragma unroll
            for (int j = 0; j < 8; ++j) f[j] = 0.0f;
        }
        bf16x8 t;
#pragma unroll
        for (int j = 0; j < 8; ++j) {
            float v = f[j];
            if (RELU_A) v = fmaxf(v, 0.0f);
            t[j] = f2bf(v);
        }
        *(bf16x8*)&As[r * 128 + ((c ^ (r & 7)) << 3)] = t;
    }
    // --- stage B: bf16 direct, swizzled ---
#pragma unroll
    for (int i = 0; i < 8; ++i) {
        int chunk = tid + (i << 8);
        int r = chunk >> 4, c = chunk & 15;
        bf16x8 v = *(const bf16x8*)&Wt[(((size_t)(col0 + r)) << 7) + (c << 3)];
        *(bf16x8*)&Bs[r * 128 + ((c ^ (r & 7)) << 3)] = v;
    }
    __syncthreads();

    const int lane = tid & 63;
    const int wid = tid >> 6;
    const int r0 = (wid >> 1) << 6;
    const int c0 = (wid & 1) << 6;
    const int lrow = lane & 15;
    const int lk = lane >> 4;

    f32x4 acc[4][4] = {};

#pragma unroll
    for (int ks = 0; ks < 4; ++ks) {
        int chunk = (ks << 2) + lk;
        bf16x8 a[4], b[4];
#pragma unroll
        for (int m = 0; m < 4; ++m) {
            int rr = r0 + (m << 4) + lrow;
            a[m] = *(const bf16x8*)&As[rr * 128 + ((chunk ^ (rr & 7)) << 3)];
        }
#pragma unroll
        for (int n = 0; n < 4; ++n) {
            int cc = c0 + (n << 4) + lrow;
            b[n] = *(const bf16x8*)&Bs[cc * 128 + ((chunk ^ (cc & 7)) << 3)];
        }
#pragma unroll
        for (int m = 0; m < 4; ++m)
#pragma unroll
            for (int n = 0; n < 4; ++n)
                acc[m][n] = __builtin_amdgcn_mfma_f32_16x16x32_bf16(a[m], b[n], acc[m][n], 0, 0, 0);
    }

    // --- epilogue: C[row][col] ; C/D map: col = lane&15, row = (lane>>4)*4+j ---
#pragma unroll
    for (int n = 0; n < 4; ++n) {
        int gc = col0 + c0 + (n << 4) + lrow;
        float bb = 0.0f;
        if (HAS_BIAS) bb = bias[gc];
#pragma unroll
        for (int m = 0; m < 4; ++m) {
#pragma unroll
            for (int j = 0; j < 4; ++j) {
                int gr = row0 + r0 + (m << 4) + (lk << 2) + j;
                if (gr < M) C[(size_t)gr * N + gc] = acc[m][n][j] + bb;
            }
        }
    }
}

// ---------------------------------------------------------------------------
// GCN aggregation, pull style: one wave per destination node.
// ---------------------------------------------------------------------------
__global__ __launch_bounds__(256) void gcn_gather_k(const float* __restrict__ HW,
                                                    const float* __restrict__ dis,
                                                    const int* __restrict__ rowptr,
                                                    const int* __restrict__ csr_src,
                                                    const float* __restrict__ csr_w,
                                                    const float* __restrict__ bias,
                                                    float* __restrict__ out, int N) {
    int node = (blockIdx.x * 256 + threadIdx.x) >> 6;
    int lane = threadIdx.x & 63;
    if (node >= N) return;
    float dd = dis[node];
    float2 hw = *(const float2*)&HW[((size_t)node << HBITS) + lane * 2];
    float2 b2 = *(const float2*)&bias[lane * 2];
    float accx = hw.x * dd * dd + b2.x;
    float accy = hw.y * dd * dd + b2.y;
    int beg = rowptr[node], end = rowptr[node + 1];
    for (int e = beg; e < end; ++e) {
        int s = csr_src[e];
        float w = csr_w[e];
        float2 v = *(const float2*)&HW[((size_t)s << HBITS) + lane * 2];
        accx += v.x * w;
        accy += v.y * w;
    }
    float2 r;
    r.x = accx;
    r.y = accy;
    *(float2*)&out[((size_t)node << HBITS) + lane * 2] = r;
}

// ---------------------------------------------------------------------------
// GRU finalize
// ---------------------------------------------------------------------------
__global__ void gru_finalize_k(const float* __restrict__ gi, const float* __restrict__ gh,
                               const float* __restrict__ h, float* __restrict__ hn, int total) {
    int idx = blockIdx.x * blockDim.x + threadIdx.x;
    if (idx >= total) return;
    int node = idx >> HBITS;
    int j = idx & (NODES_H - 1);
    size_t b = (size_t)node * 384;
    float ir = gi[b + j], iz = gi[b + 128 + j], in_ = gi[b + 256 + j];
    float hr = gh[b + j], hz = gh[b + 128 + j], hn_ = gh[b + 256 + j];
    float r = 1.0f / (1.0f + expf(-(ir + hr)));
    float z = 1.0f / (1.0f + expf(-(iz + hz)));
    float n = tanhf(in_ + r * hn_);
    hn[idx] = (1.0f - z) * n + z * h[idx];
}

// ---------------------------------------------------------------------------
// Output head
// ---------------------------------------------------------------------------
#define OUT_DIM 5
__global__ void out_softmax_k(const float* __restrict__ h, const float* __restrict__ Wo,
                              const float* __restrict__ bo, float* __restrict__ out, int N) {
    int gtid = blockIdx.x * blockDim.x + threadIdx.x;
    int node = gtid >> 6;
    int lane = threadIdx.x & 63;
    if (node >= N) return;
    const float* hr = h + ((size_t)node << HBITS);
    float h0 = hr[lane];
    float h1 = hr[lane + 64];
    float acc[OUT_DIM];
#pragma unroll
    for (int o = 0; o < OUT_DIM; ++o)
        acc[o] = h0 * Wo[lane * OUT_DIM + o] + h1 * Wo[(lane + 64) * OUT_DIM + o];
#pragma unroll
    for (int off = 32; off >= 1; off >>= 1) {
#pragma unroll
        for (int o = 0; o < OUT_DIM; ++o) acc[o] += __shfl_down(acc[o], off, 64);
    }
    if (lane == 0) {
        float v[OUT_DIM], m = -1e30f;
#pragma unroll
        for (int o = 0; o < OUT_DIM; ++o) { v[o] = acc[o] + bo[o]; m = fmaxf(m, v[o]); }
        float s = 0.0f;
#pragma unroll
        for (int o = 0; o < OUT_DIM; ++o) { v[o] = expf(v[o] - m); s += v[o]; }
        float inv = 1.0f / s;
#pragma unroll
        for (int o = 0; o < OUT_DIM; ++o) out[(size_t)node * OUT_DIM + o] = v[o] * inv;
    }
}

// ---------------------------------------------------------------------------
// launch
// ---------------------------------------------------------------------------
static inline int cdiv(long long a, long long b) { return (int)((a + b - 1) / b); }

extern "C" void kernel_launch(void* const* d_in, const int* in_sizes, int n_in,
                              void* d_out, int out_size, void* d_ws, size_t ws_size,
                              hipStream_t stream) {
    const float* x       = (const float*)d_in[0];
    const int*   eidx    = (const int*)d_in[1];
    const float* proj_W  = (const float*)d_in[2];
    const float* proj_b  = (const float*)d_in[3];
    const float* conv1_W = (const float*)d_in[4];
    const float* conv1_b = (const float*)d_in[5];
    const float* conv2_W = (const float*)d_in[6];
    const float* conv2_b = (const float*)d_in[7];
    const float* hidden_c= (const float*)d_in[8];
    const float* gru_Wih = (const float*)d_in[9];
    const float* gru_Whh = (const float*)d_in[10];
    const float* gru_bih = (const float*)d_in[11];
    const float* gru_bhh = (const float*)d_in[12];
    const float* out_W   = (const float*)d_in[13];
    const float* out_b   = (const float*)d_in[14];
    float* out = (float*)d_out;

    const int F = 16, H = 128, G3 = 384;
    const int N = in_sizes[0] / F;
    const int E = in_sizes[1] / 2;
    const int* src = eidx;
    const int* dst = eidx + E;

    const int TPB = 256;
    const int nScanBlocks = cdiv(N, 256);

    // workspace layout
    char* wp = (char*)d_ws;
    int*   cnt     = (int*)wp;              wp += (size_t)N * 4;
    int*   rowptr  = (int*)wp;              wp += (size_t)(N + 1) * 4;
    int*   pos     = (int*)wp;              wp += (size_t)N * 4;
    int*   bsum    = (int*)wp;              wp += 256 * 4;
    int*   csr_src = (int*)wp;              wp += (size_t)E * 4;
    float* csr_w   = (float*)wp;            wp += (size_t)E * 4;
    float* dis     = (float*)wp;            wp += (size_t)N * 4;
    short* c1Wt    = (short*)wp;            wp += (size_t)H * H * 2;
    short* c2Wt    = (short*)wp;            wp += (size_t)H * H * 2;
    short* WihT    = (short*)wp;            wp += (size_t)G3 * H * 2;
    short* WhhT    = (short*)wp;            wp += (size_t)G3 * H * 2;
    float* h0      = (float*)wp;            wp += (size_t)N * H * 4;
    float* h1      = (float*)wp;            wp += (size_t)N * H * 4;
    float* Abuf    = (float*)wp;            wp += (size_t)N * H * 4;
    float* G1      = (float*)wp;            wp += (size_t)N * G3 * 4;
    float* G2      = (float*)wp;            wp += (size_t)N * G3 * 4;
    float* HW      = G2;  // alias

    const int totNH = N * H;

    // --- weight preconversion (bf16, [n][k] layout) ---
    cvt_bf16_t_k<<<cdiv(H * H, TPB), TPB, 0, stream>>>(conv1_W, c1Wt, H, H);
    cvt_bf16_t_k<<<cdiv(H * H, TPB), TPB, 0, stream>>>(conv2_W, c2Wt, H, H);
    cvt_bf16_k<<<cdiv(G3 * H, TPB), TPB, 0, stream>>>(gru_Wih, WihT, G3 * H);
    cvt_bf16_k<<<cdiv(G3 * H, TPB), TPB, 0, stream>>>(gru_Whh, WhhT, G3 * H);

    // --- CSR build + normalization ---
    zero_cnt_k<<<cdiv(N, TPB), TPB, 0, stream>>>(cnt, N);
    count_k<<<cdiv(E, TPB), TPB, 0, stream>>>(dst, cnt, E);
    scan1_k<<<nScanBlocks, 256, 0, stream>>>(cnt, rowptr, bsum, N);
    scan2_k<<<1, 256, 0, stream>>>(bsum, nScanBlocks);
    scan3_k<<<nScanBlocks, 256, 0, stream>>>(rowptr, bsum, cnt, pos, dis, N, E);
    reorder_k<<<cdiv(E, TPB), TPB, 0, stream>>>(src, dst, dis, pos, csr_src, csr_w, E);

    // --- h = broadcast(hidden_c) ---
    h_init_k<<<cdiv(totNH, TPB), TPB, 0, stream>>>(hidden_c, h0, totNH);

    float* h_cur = h0;
    float* h_nxt = h1;

    const int gmM = cdiv(N, 128);                 // MFMA row blocks
    dim3 gridMH(gmM * (H / 128));                 // N=128 -> gn=1
    dim3 gridMG(gmM * (G3 / 128));                // N=384 -> gn=3
    const int gatherBlocks = cdiv((long long)N * 64, TPB);

    // --- proj (K=16, fp32 path) ---
    dim3 gridP(cdiv(N, BM) * (H / BN));
    gemm_k<false, false><<<gridP, TPB, 0, stream>>>(x, proj_W, proj_b, Abuf, N, F, H);

    // --- GRU step 0 ---
    gemm_mfma_k<false, true><<<gridMG, TPB, 0, stream>>>(Abuf, WihT, gru_bih, G1, N, G3);
    gemm_mfma_k<false, true><<<gridMG, TPB, 0, stream>>>(h_cur, WhhT, gru_bhh, G2, N, G3);
    gru_finalize_k<<<cdiv(totNH, TPB), TPB, 0, stream>>>(G1, G2, h_cur, h_nxt, totNH);
    { float* t = h_cur; h_cur = h_nxt; h_nxt = t; }

    for (int it = 0; it < 3; ++it) {
        gemm_mfma_k<false, false><<<gridMH, TPB, 0, stream>>>(h_cur, c1Wt, nullptr, HW, N, H);
        gcn_gather_k<<<gatherBlocks, TPB, 0, stream>>>(HW, dis, rowptr, csr_src, csr_w,
                                                       conv1_b, Abuf, N);
        gemm_mfma_k<true, false><<<gridMH, TPB, 0, stream>>>(Abuf, c2Wt, nullptr, HW, N, H);
        gcn_gather_k<<<gatherBlocks, TPB, 0, stream>>>(HW, dis, rowptr, csr_src, csr_w,
                                                       conv2_b, Abuf, N);
        gemm_mfma_k<true, true><<<gridMG, TPB, 0, stream>>>(Abuf, WihT, gru_bih, G1, N, G3);
        gemm_mfma_k<false, true><<<gridMG, TPB, 0, stream>>>(h_cur, WhhT, gru_bhh, G2, N, G3);
        gru_finalize_k<<<cdiv(totNH, TPB), TPB, 0, stream>>>(G1, G2, h_cur, h_nxt, totNH);
        { float* t = h_cur; h_cur = h_nxt; h_nxt = t; }
    }

    // --- output head ---
    out_softmax_k<<<cdiv((long long)N * 64, TPB), TPB, 0, stream>>>(h_cur, out_W, out_b, out, N);
}

// Round 4
// 956.190 us; speedup vs baseline: 3.7148x; 1.3562x over previous
//
#include <hip/hip_runtime.h>
#include <hip/hip_bf16.h>

#define NODES_H 128
#define HBITS 7   // 128 = 1<<7

typedef __attribute__((ext_vector_type(8))) short bf16x8;
typedef __attribute__((ext_vector_type(4))) float f32x4;

static __device__ __forceinline__ short f2bf(float f) {
    union { float f; unsigned u; } v; v.f = f;
    unsigned r = v.u + 0x7FFFu + ((v.u >> 16) & 1u);  // RNE
    return (short)(r >> 16);
}
static __device__ __forceinline__ float bf2f(unsigned short u) {
    union { unsigned u; float f; } v; v.u = ((unsigned)u) << 16;
    return v.f;
}

// ---------------------------------------------------------------------------
// weight preconversion
// ---------------------------------------------------------------------------
__global__ void cvt_bf16_k(const float* __restrict__ in, short* __restrict__ out, int n) {
    int i = blockIdx.x * blockDim.x + threadIdx.x;
    if (i < n) out[i] = f2bf(in[i]);
}

__global__ void cvt_bf16_t_k(const float* __restrict__ in, short* __restrict__ out, int K, int N) {
    int i = blockIdx.x * blockDim.x + threadIdx.x;
    if (i >= K * N) return;
    int nn = i >> HBITS;
    int kk = i & (NODES_H - 1);
    out[i] = f2bf(in[kk * N + nn]);  // out[n][k] = in[k][n], K==128
}

// ---------------------------------------------------------------------------
// CSR build
// ---------------------------------------------------------------------------
__global__ void zero_cnt_k(int* __restrict__ cnt, int N) {
    int i = blockIdx.x * blockDim.x + threadIdx.x;
    if (i < N) cnt[i] = 0;
}

__global__ void count_k(const int* __restrict__ dst, int* __restrict__ cnt, int E) {
    int e = blockIdx.x * blockDim.x + threadIdx.x;
    if (e < E) atomicAdd(&cnt[dst[e]], 1);
}

__global__ __launch_bounds__(256) void scan1_k(const int* __restrict__ cnt,
                                               int* __restrict__ rowptr,
                                               int* __restrict__ bsum, int N) {
    __shared__ int buf[256];
    int tid = threadIdx.x;
    int i = blockIdx.x * 256 + tid;
    int v = (i < N) ? cnt[i] : 0;
    buf[tid] = v;
    __syncthreads();
#pragma unroll
    for (int off = 1; off < 256; off <<= 1) {
        int t = (tid >= off) ? buf[tid - off] : 0;
        __syncthreads();
        buf[tid] += t;
        __syncthreads();
    }
    if (i < N) rowptr[i] = buf[tid] - v;
    if (tid == 255) bsum[blockIdx.x] = buf[255];
}

__global__ __launch_bounds__(256) void scan2_k(int* __restrict__ bsum, int nb) {
    __shared__ int buf[256];
    int tid = threadIdx.x;
    int v = (tid < nb) ? bsum[tid] : 0;
    buf[tid] = v;
    __syncthreads();
#pragma unroll
    for (int off = 1; off < 256; off <<= 1) {
        int t = (tid >= off) ? buf[tid - off] : 0;
        __syncthreads();
        buf[tid] += t;
        __syncthreads();
    }
    if (tid < nb) bsum[tid] = buf[tid] - v;
}

__global__ void scan3_k(int* __restrict__ rowptr, const int* __restrict__ bsum,
                        const int* __restrict__ cnt, int* __restrict__ pos,
                        float* __restrict__ dis, int N, int E) {
    int i = blockIdx.x * blockDim.x + threadIdx.x;
    if (i < N) {
        int v = rowptr[i] + bsum[blockIdx.x];
        rowptr[i] = v;
        pos[i] = v;
        dis[i] = rsqrtf((float)(cnt[i] + 1));
    }
    if (i == 0) rowptr[N] = E;
}

__global__ void reorder_k(const int* __restrict__ src, const int* __restrict__ dst,
                          const float* __restrict__ dis, int* __restrict__ pos,
                          int* __restrict__ csr_src, float* __restrict__ csr_w, int E) {
    int e = blockIdx.x * blockDim.x + threadIdx.x;
    if (e >= E) return;
    int s = src[e], d = dst[e];
    int p = atomicAdd(&pos[d], 1);
    csr_src[p] = s;
    csr_w[p] = dis[s] * dis[d];
}

// ---------------------------------------------------------------------------
// h init: fp32 + bf16 mirror
// ---------------------------------------------------------------------------
__global__ void h_init_k(const float* __restrict__ hc, float* __restrict__ h,
                         unsigned short* __restrict__ hb, int total) {
    int i = blockIdx.x * blockDim.x + threadIdx.x;
    if (i < total) {
        float v = hc[i & (NODES_H - 1)];
        h[i] = v;
        hb[i] = (unsigned short)f2bf(v);
    }
}

// ---------------------------------------------------------------------------
// fp32 tiled GEMM (proj: K=16), bf16 output
// ---------------------------------------------------------------------------
#define BM 64
#define BN 64
#define BK 16

template <bool WT, bool RELU_A>
__global__ __launch_bounds__(256) void gemm_k(const float* __restrict__ A,
                                              const float* __restrict__ W,
                                              const float* __restrict__ bias,
                                              unsigned short* __restrict__ C,
                                              int M, int K, int N) {
    __shared__ float As[BK][BM + 1];
    __shared__ float Ws[BK][BN + 1];

    const int gn = N / BN;
    const int bx = blockIdx.x % gn;
    const int by = blockIdx.x / gn;
    const int tid = threadIdx.x;
    const int tx = tid & 15;
    const int ty = tid >> 4;
    const int row0 = by * BM;
    const int col0 = bx * BN;

    float acc[4][4] = {};

    for (int k0 = 0; k0 < K; k0 += BK) {
#pragma unroll
        for (int i = 0; i < 4; ++i) {
            int idx = tid + i * 256;
            int r = idx >> 4, k = idx & 15;
            int gr = row0 + r;
            float v = (gr < M) ? A[(size_t)gr * K + k0 + k] : 0.0f;
            if (RELU_A) v = fmaxf(v, 0.0f);
            As[k][r] = v;
        }
#pragma unroll
        for (int i = 0; i < 4; ++i) {
            int idx = tid + i * 256;
            if (!WT) {
                int k = idx >> 6, n = idx & 63;
                Ws[k][n] = W[(size_t)(k0 + k) * N + col0 + n];
            } else {
                int n = idx >> 4, k = idx & 15;
                Ws[k][n] = W[(size_t)(col0 + n) * K + k0 + k];
            }
        }
        __syncthreads();

#pragma unroll
        for (int kk = 0; kk < BK; ++kk) {
            float a[4], w[4];
#pragma unroll
            for (int i = 0; i < 4; ++i) a[i] = As[kk][ty * 4 + i];
#pragma unroll
            for (int j = 0; j < 4; ++j) w[j] = Ws[kk][tx * 4 + j];
#pragma unroll
            for (int i = 0; i < 4; ++i)
#pragma unroll
                for (int j = 0; j < 4; ++j) acc[i][j] += a[i] * w[j];
        }
        __syncthreads();
    }

#pragma unroll
    for (int i = 0; i < 4; ++i) {
        int gr = row0 + ty * 4 + i;
        if (gr >= M) continue;
#pragma unroll
        for (int j = 0; j < 4; ++j) {
            int gc = col0 + tx * 4 + j;
            float v = acc[i][j];
            if (bias) v += bias[gc];
            C[(size_t)gr * N + gc] = (unsigned short)f2bf(v);
        }
    }
}

// ---------------------------------------------------------------------------
// bf16 MFMA GEMM: C[M,N] = relu?(A bf16 [M,128]) @ Wt^T + bias
//   Wt bf16 [N][128]. K fixed 128. OUT_BF16 selects output type.
// 128x128 tile, 4 waves, mfma_f32_16x16x32_bf16, XOR-swizzled LDS.
// ---------------------------------------------------------------------------
template <bool RELU_A, bool HAS_BIAS, bool OUT_BF16>
__global__ __launch_bounds__(256) void gemm_mfma_k(const unsigned short* __restrict__ A,
                                                   const short* __restrict__ Wt,
                                                   const float* __restrict__ bias,
                                                   void* __restrict__ Cv,
                                                   int M, int N) {
    __shared__ short As[128 * 128];
    __shared__ short Bs[128 * 128];

    const int gn = N >> 7;
    const int bx = blockIdx.x % gn;
    const int by = blockIdx.x / gn;
    const int row0 = by << 7, col0 = bx << 7;
    const int tid = threadIdx.x;

    // --- stage A: bf16 direct copy, swizzled (relu = sign-bit test) ---
#pragma unroll
    for (int i = 0; i < 8; ++i) {
        int chunk = tid + (i << 8);
        int r = chunk >> 4, c = chunk & 15;
        int gr = row0 + r;
        bf16x8 t;
        if (gr < M) {
            t = *(const bf16x8*)(A + (((size_t)gr) << 7) + (c << 3));
            if (RELU_A) {
#pragma unroll
                for (int j = 0; j < 8; ++j) {
                    unsigned short u = (unsigned short)t[j];
                    t[j] = (short)((u & 0x8000u) ? 0 : u);
                }
            }
        } else {
#pragma unroll
            for (int j = 0; j < 8; ++j) t[j] = 0;
        }
        *(bf16x8*)&As[r * 128 + ((c ^ (r & 7)) << 3)] = t;
    }
    // --- stage B ---
#pragma unroll
    for (int i = 0; i < 8; ++i) {
        int chunk = tid + (i << 8);
        int r = chunk >> 4, c = chunk & 15;
        bf16x8 v = *(const bf16x8*)&Wt[(((size_t)(col0 + r)) << 7) + (c << 3)];
        *(bf16x8*)&Bs[r * 128 + ((c ^ (r & 7)) << 3)] = v;
    }
    __syncthreads();

    const int lane = tid & 63;
    const int wid = tid >> 6;
    const int r0 = (wid >> 1) << 6;
    const int c0 = (wid & 1) << 6;
    const int lrow = lane & 15;
    const int lk = lane >> 4;

    f32x4 acc[4][4] = {};

#pragma unroll
    for (int ks = 0; ks < 4; ++ks) {
        int chunk = (ks << 2) + lk;
        bf16x8 a[4], b[4];
#pragma unroll
        for (int m = 0; m < 4; ++m) {
            int rr = r0 + (m << 4) + lrow;
            a[m] = *(const bf16x8*)&As[rr * 128 + ((chunk ^ (rr & 7)) << 3)];
        }
#pragma unroll
        for (int n = 0; n < 4; ++n) {
            int cc = c0 + (n << 4) + lrow;
            b[n] = *(const bf16x8*)&Bs[cc * 128 + ((chunk ^ (cc & 7)) << 3)];
        }
#pragma unroll
        for (int m = 0; m < 4; ++m)
#pragma unroll
            for (int n = 0; n < 4; ++n)
                acc[m][n] = __builtin_amdgcn_mfma_f32_16x16x32_bf16(a[m], b[n], acc[m][n], 0, 0, 0);
    }

    // --- epilogue: C/D map: col = lane&15, row = (lane>>4)*4+j ---
#pragma unroll
    for (int n = 0; n < 4; ++n) {
        int gc = col0 + c0 + (n << 4) + lrow;
        float bb = 0.0f;
        if (HAS_BIAS) bb = bias[gc];
#pragma unroll
        for (int m = 0; m < 4; ++m) {
#pragma unroll
            for (int j = 0; j < 4; ++j) {
                int gr = row0 + r0 + (m << 4) + (lk << 2) + j;
                if (gr < M) {
                    float v = acc[m][n][j] + bb;
                    if (OUT_BF16)
                        ((unsigned short*)Cv)[(size_t)gr * N + gc] = (unsigned short)f2bf(v);
                    else
                        ((float*)Cv)[(size_t)gr * N + gc] = v;
                }
            }
        }
    }
}

// ---------------------------------------------------------------------------
// GCN gather (pull): one wave per destination node, bf16 HW rows.
// out[d] = HW[d]*dis[d]^2 + bias + sum_e w[e]*HW[src[e]]  (bf16 out)
// lane owns cols {2l, 2l+1} (one dword per row-read).
// ---------------------------------------------------------------------------
__global__ __launch_bounds__(256) void gcn_gather_k(const unsigned short* __restrict__ HW,
                                                    const float* __restrict__ dis,
                                                    const int* __restrict__ rowptr,
                                                    const int* __restrict__ csr_src,
                                                    const float* __restrict__ csr_w,
                                                    const float* __restrict__ bias,
                                                    unsigned short* __restrict__ out, int N) {
    int node = (blockIdx.x * 256 + threadIdx.x) >> 6;
    int lane = threadIdx.x & 63;
    if (node >= N) return;
    float dd = dis[node];
    unsigned v0 = *(const unsigned*)&HW[((size_t)node << HBITS) + (lane << 1)];
    float2 b2 = *(const float2*)&bias[lane << 1];
    float accx = bf2f((unsigned short)(v0 & 0xFFFFu)) * dd * dd + b2.x;
    float accy = bf2f((unsigned short)(v0 >> 16)) * dd * dd + b2.y;
    int e = rowptr[node], end = rowptr[node + 1];
    for (; e + 1 < end; e += 2) {
        int s0 = csr_src[e], s1 = csr_src[e + 1];
        float w0 = csr_w[e], w1 = csr_w[e + 1];
        unsigned a = *(const unsigned*)&HW[((size_t)s0 << HBITS) + (lane << 1)];
        unsigned b = *(const unsigned*)&HW[((size_t)s1 << HBITS) + (lane << 1)];
        accx += bf2f((unsigned short)(a & 0xFFFFu)) * w0;
        accy += bf2f((unsigned short)(a >> 16)) * w0;
        accx += bf2f((unsigned short)(b & 0xFFFFu)) * w1;
        accy += bf2f((unsigned short)(b >> 16)) * w1;
    }
    if (e < end) {
        int s = csr_src[e];
        float w = csr_w[e];
        unsigned a = *(const unsigned*)&HW[((size_t)s << HBITS) + (lane << 1)];
        accx += bf2f((unsigned short)(a & 0xFFFFu)) * w;
        accy += bf2f((unsigned short)(a >> 16)) * w;
    }
    unsigned o = ((unsigned)(unsigned short)f2bf(accy) << 16) | (unsigned short)f2bf(accx);
    *(unsigned*)&out[((size_t)node << HBITS) + (lane << 1)] = o;
}

// ---------------------------------------------------------------------------
// GRU finalize: h' = (1-z)*n + z*h ; writes fp32 h + bf16 mirror
// ---------------------------------------------------------------------------
__global__ void gru_finalize_k(const float* __restrict__ gi, const float* __restrict__ gh,
                               const float* __restrict__ h, float* __restrict__ hn,
                               unsigned short* __restrict__ hnb, int total) {
    int idx = blockIdx.x * blockDim.x + threadIdx.x;
    if (idx >= total) return;
    int node = idx >> HBITS;
    int j = idx & (NODES_H - 1);
    size_t b = (size_t)node * 384;
    float ir = gi[b + j], iz = gi[b + 128 + j], in_ = gi[b + 256 + j];
    float hr = gh[b + j], hz = gh[b + 128 + j], hn_ = gh[b + 256 + j];
    float r = 1.0f / (1.0f + expf(-(ir + hr)));
    float z = 1.0f / (1.0f + expf(-(iz + hz)));
    float n = tanhf(in_ + r * hn_);
    float v = (1.0f - z) * n + z * h[idx];
    hn[idx] = v;
    hnb[idx] = (unsigned short)f2bf(v);
}

// ---------------------------------------------------------------------------
// Output head
// ---------------------------------------------------------------------------
#define OUT_DIM 5
__global__ void out_softmax_k(const float* __restrict__ h, const float* __restrict__ Wo,
                              const float* __restrict__ bo, float* __restrict__ out, int N) {
    int gtid = blockIdx.x * blockDim.x + threadIdx.x;
    int node = gtid >> 6;
    int lane = threadIdx.x & 63;
    if (node >= N) return;
    const float* hr = h + ((size_t)node << HBITS);
    float h0 = hr[lane];
    float h1 = hr[lane + 64];
    float acc[OUT_DIM];
#pragma unroll
    for (int o = 0; o < OUT_DIM; ++o)
        acc[o] = h0 * Wo[lane * OUT_DIM + o] + h1 * Wo[(lane + 64) * OUT_DIM + o];
#pragma unroll
    for (int off = 32; off >= 1; off >>= 1) {
#pragma unroll
        for (int o = 0; o < OUT_DIM; ++o) acc[o] += __shfl_down(acc[o], off, 64);
    }
    if (lane == 0) {
        float v[OUT_DIM], m = -1e30f;
#pragma unroll
        for (int o = 0; o < OUT_DIM; ++o) { v[o] = acc[o] + bo[o]; m = fmaxf(m, v[o]); }
        float s = 0.0f;
#pragma unroll
        for (int o = 0; o < OUT_DIM; ++o) { v[o] = expf(v[o] - m); s += v[o]; }
        float inv = 1.0f / s;
#pragma unroll
        for (int o = 0; o < OUT_DIM; ++o) out[(size_t)node * OUT_DIM + o] = v[o] * inv;
    }
}

// ---------------------------------------------------------------------------
// launch
// ---------------------------------------------------------------------------
static inline int cdiv(long long a, long long b) { return (int)((a + b - 1) / b); }
static inline char* align256(char* p) {
    return (char*)(((uintptr_t)p + 255) & ~(uintptr_t)255);
}

extern "C" void kernel_launch(void* const* d_in, const int* in_sizes, int n_in,
                              void* d_out, int out_size, void* d_ws, size_t ws_size,
                              hipStream_t stream) {
    const float* x       = (const float*)d_in[0];
    const int*   eidx    = (const int*)d_in[1];
    const float* proj_W  = (const float*)d_in[2];
    const float* proj_b  = (const float*)d_in[3];
    const float* conv1_W = (const float*)d_in[4];
    const float* conv1_b = (const float*)d_in[5];
    const float* conv2_W = (const float*)d_in[6];
    const float* conv2_b = (const float*)d_in[7];
    const float* hidden_c= (const float*)d_in[8];
    const float* gru_Wih = (const float*)d_in[9];
    const float* gru_Whh = (const float*)d_in[10];
    const float* gru_bih = (const float*)d_in[11];
    const float* gru_bhh = (const float*)d_in[12];
    const float* out_W   = (const float*)d_in[13];
    const float* out_b   = (const float*)d_in[14];
    float* out = (float*)d_out;

    const int F = 16, H = 128, G3 = 384;
    const int N = in_sizes[0] / F;
    const int E = in_sizes[1] / 2;
    const int* src = eidx;
    const int* dst = eidx + E;

    const int TPB = 256;
    const int nScanBlocks = cdiv(N, 256);

    // workspace (256B-aligned slots)
    char* wp = (char*)d_ws;
#define ALLOC(ptr_t, name, bytes) ptr_t name = (ptr_t)wp; wp = align256(wp + (bytes))
    ALLOC(int*, cnt, (size_t)N * 4);
    ALLOC(int*, rowptr, (size_t)(N + 1) * 4);
    ALLOC(int*, pos, (size_t)N * 4);
    ALLOC(int*, bsum, 256 * 4);
    ALLOC(int*, csr_src, (size_t)E * 4);
    ALLOC(float*, csr_w, (size_t)E * 4);
    ALLOC(float*, dis, (size_t)N * 4);
    ALLOC(short*, c1Wt, (size_t)H * H * 2);
    ALLOC(short*, c2Wt, (size_t)H * H * 2);
    ALLOC(short*, WihT, (size_t)G3 * H * 2);
    ALLOC(short*, WhhT, (size_t)G3 * H * 2);
    ALLOC(float*, h0, (size_t)N * H * 4);
    ALLOC(float*, h1, (size_t)N * H * 4);
    ALLOC(unsigned short*, h0b, (size_t)N * H * 2);
    ALLOC(unsigned short*, h1b, (size_t)N * H * 2);
    ALLOC(unsigned short*, Abuf, (size_t)N * H * 2);
    ALLOC(float*, G1, (size_t)N * G3 * 4);
    ALLOC(float*, G2, (size_t)N * G3 * 4);
#undef ALLOC
    unsigned short* HWb = (unsigned short*)G2;  // alias: disjoint lifetimes

    const int totNH = N * H;

    // --- weight preconversion (bf16, [n][k]) ---
    cvt_bf16_t_k<<<cdiv(H * H, TPB), TPB, 0, stream>>>(conv1_W, c1Wt, H, H);
    cvt_bf16_t_k<<<cdiv(H * H, TPB), TPB, 0, stream>>>(conv2_W, c2Wt, H, H);
    cvt_bf16_k<<<cdiv(G3 * H, TPB), TPB, 0, stream>>>(gru_Wih, WihT, G3 * H);
    cvt_bf16_k<<<cdiv(G3 * H, TPB), TPB, 0, stream>>>(gru_Whh, WhhT, G3 * H);

    // --- CSR build + normalization ---
    zero_cnt_k<<<cdiv(N, TPB), TPB, 0, stream>>>(cnt, N);
    count_k<<<cdiv(E, TPB), TPB, 0, stream>>>(dst, cnt, E);
    scan1_k<<<nScanBlocks, 256, 0, stream>>>(cnt, rowptr, bsum, N);
    scan2_k<<<1, 256, 0, stream>>>(bsum, nScanBlocks);
    scan3_k<<<nScanBlocks, 256, 0, stream>>>(rowptr, bsum, cnt, pos, dis, N, E);
    reorder_k<<<cdiv(E, TPB), TPB, 0, stream>>>(src, dst, dis, pos, csr_src, csr_w, E);

    // --- h init ---
    h_init_k<<<cdiv(totNH, TPB), TPB, 0, stream>>>(hidden_c, h0, h0b, totNH);

    float* h_cur = h0;          float* h_nxt = h1;
    unsigned short* hb_cur = h0b; unsigned short* hb_nxt = h1b;

    const int gmM = cdiv(N, 128);
    dim3 gridMH(gmM * (H / 128));
    dim3 gridMG(gmM * (G3 / 128));
    const int gatherBlocks = cdiv((long long)N * 64, TPB);

    // --- proj (K=16, fp32 path, bf16 out) ---
    dim3 gridP(cdiv(N, BM) * (H / BN));
    gemm_k<false, false><<<gridP, TPB, 0, stream>>>(x, proj_W, proj_b, Abuf, N, F, H);

    // --- GRU step 0 ---
    gemm_mfma_k<false, true, false><<<gridMG, TPB, 0, stream>>>(Abuf, WihT, gru_bih, G1, N, G3);
    gemm_mfma_k<false, true, false><<<gridMG, TPB, 0, stream>>>(hb_cur, WhhT, gru_bhh, G2, N, G3);
    gru_finalize_k<<<cdiv(totNH, TPB), TPB, 0, stream>>>(G1, G2, h_cur, h_nxt, hb_nxt, totNH);
    { float* t = h_cur; h_cur = h_nxt; h_nxt = t; }
    { unsigned short* t = hb_cur; hb_cur = hb_nxt; hb_nxt = t; }

    for (int it = 0; it < 3; ++it) {
        gemm_mfma_k<false, false, true><<<gridMH, TPB, 0, stream>>>(hb_cur, c1Wt, nullptr, HWb, N, H);
        gcn_gather_k<<<gatherBlocks, TPB, 0, stream>>>(HWb, dis, rowptr, csr_src, csr_w,
                                                       conv1_b, Abuf, N);
        gemm_mfma_k<true, false, true><<<gridMH, TPB, 0, stream>>>(Abuf, c2Wt, nullptr, HWb, N, H);
        gcn_gather_k<<<gatherBlocks, TPB, 0, stream>>>(HWb, dis, rowptr, csr_src, csr_w,
                                                       conv2_b, Abuf, N);
        gemm_mfma_k<true, true, false><<<gridMG, TPB, 0, stream>>>(Abuf, WihT, gru_bih, G1, N, G3);
        gemm_mfma_k<false, true, false><<<gridMG, TPB, 0, stream>>>(hb_cur, WhhT, gru_bhh, G2, N, G3);
        gru_finalize_k<<<cdiv(totNH, TPB), TPB, 0, stream>>>(G1, G2, h_cur, h_nxt, hb_nxt, totNH);
        { float* t = h_cur; h_cur = h_nxt; h_nxt = t; }
        { unsigned short* t = hb_cur; hb_cur = hb_nxt; hb_nxt = t; }
    }

    // --- output head ---
    out_softmax_k<<<cdiv((long long)N * 64, TPB), TPB, 0, stream>>>(h_cur, out_W, out_b, out, N);
}

// Round 5
// 837.282 us; speedup vs baseline: 4.2424x; 1.1420x over previous
//
#include <hip/hip_runtime.h>
#include <hip/hip_bf16.h>

#define NODES_H 128
#define HBITS 7   // 128 = 1<<7

typedef __attribute__((ext_vector_type(8))) short bf16x8;
typedef __attribute__((ext_vector_type(4))) float f32x4;

static __device__ __forceinline__ short f2bf(float f) {
    union { float f; unsigned u; } v; v.f = f;
    unsigned r = v.u + 0x7FFFu + ((v.u >> 16) & 1u);  // RNE
    return (short)(r >> 16);
}
static __device__ __forceinline__ float bf2f(unsigned short u) {
    union { unsigned u; float f; } v; v.u = ((unsigned)u) << 16;
    return v.f;
}
static __device__ __forceinline__ float sigmoidf_(float x) {
    return 1.0f / (1.0f + expf(-x));
}

// ---------------------------------------------------------------------------
// weight preconversion
// ---------------------------------------------------------------------------
__global__ void cvt_bf16_k(const float* __restrict__ in, short* __restrict__ out, int n) {
    int i = blockIdx.x * blockDim.x + threadIdx.x;
    if (i < n) out[i] = f2bf(in[i]);
}

__global__ void cvt_bf16_t_k(const float* __restrict__ in, short* __restrict__ out, int K, int N) {
    int i = blockIdx.x * blockDim.x + threadIdx.x;
    if (i >= K * N) return;
    int nn = i >> HBITS;
    int kk = i & (NODES_H - 1);
    out[i] = f2bf(in[kk * N + nn]);  // out[n][k] = in[k][n], K==128
}

// ---------------------------------------------------------------------------
// CSR build
// ---------------------------------------------------------------------------
__global__ void zero_cnt_k(int* __restrict__ cnt, int N) {
    int i = blockIdx.x * blockDim.x + threadIdx.x;
    if (i < N) cnt[i] = 0;
}

__global__ void count_k(const int* __restrict__ dst, int* __restrict__ cnt, int E) {
    int e = blockIdx.x * blockDim.x + threadIdx.x;
    if (e < E) atomicAdd(&cnt[dst[e]], 1);
}

__global__ __launch_bounds__(256) void scan1_k(const int* __restrict__ cnt,
                                               int* __restrict__ rowptr,
                                               int* __restrict__ bsum, int N) {
    __shared__ int buf[256];
    int tid = threadIdx.x;
    int i = blockIdx.x * 256 + tid;
    int v = (i < N) ? cnt[i] : 0;
    buf[tid] = v;
    __syncthreads();
#pragma unroll
    for (int off = 1; off < 256; off <<= 1) {
        int t = (tid >= off) ? buf[tid - off] : 0;
        __syncthreads();
        buf[tid] += t;
        __syncthreads();
    }
    if (i < N) rowptr[i] = buf[tid] - v;
    if (tid == 255) bsum[blockIdx.x] = buf[255];
}

__global__ __launch_bounds__(256) void scan2_k(int* __restrict__ bsum, int nb) {
    __shared__ int buf[256];
    int tid = threadIdx.x;
    int v = (tid < nb) ? bsum[tid] : 0;
    buf[tid] = v;
    __syncthreads();
#pragma unroll
    for (int off = 1; off < 256; off <<= 1) {
        int t = (tid >= off) ? buf[tid - off] : 0;
        __syncthreads();
        buf[tid] += t;
        __syncthreads();
    }
    if (tid < nb) bsum[tid] = buf[tid] - v;
}

__global__ void scan3_k(int* __restrict__ rowptr, const int* __restrict__ bsum,
                        const int* __restrict__ cnt, int* __restrict__ pos,
                        float* __restrict__ dis, int N, int E) {
    int i = blockIdx.x * blockDim.x + threadIdx.x;
    if (i < N) {
        int v = rowptr[i] + bsum[blockIdx.x];
        rowptr[i] = v;
        pos[i] = v;
        dis[i] = rsqrtf((float)(cnt[i] + 1));
    }
    if (i == 0) rowptr[N] = E;
}

__global__ void reorder_k(const int* __restrict__ src, const int* __restrict__ dst,
                          int* __restrict__ pos, int* __restrict__ csr_src, int E) {
    int e = blockIdx.x * blockDim.x + threadIdx.x;
    if (e >= E) return;
    int p = atomicAdd(&pos[dst[e]], 1);
    csr_src[p] = src[e];
}

// ---------------------------------------------------------------------------
// h init: fp32 + bf16 mirror
// ---------------------------------------------------------------------------
__global__ void h_init_k(const float* __restrict__ hc, float* __restrict__ h,
                         unsigned short* __restrict__ hb, int total) {
    int i = blockIdx.x * blockDim.x + threadIdx.x;
    if (i < total) {
        float v = hc[i & (NODES_H - 1)];
        h[i] = v;
        hb[i] = (unsigned short)f2bf(v);
    }
}

// ---------------------------------------------------------------------------
// fp32 tiled GEMM (proj: K=16), bf16 output
// ---------------------------------------------------------------------------
#define BM 64
#define BN 64
#define BK 16

template <bool WT, bool RELU_A>
__global__ __launch_bounds__(256) void gemm_k(const float* __restrict__ A,
                                              const float* __restrict__ W,
                                              const float* __restrict__ bias,
                                              unsigned short* __restrict__ C,
                                              int M, int K, int N) {
    __shared__ float As[BK][BM + 1];
    __shared__ float Ws[BK][BN + 1];

    const int gn = N / BN;
    const int bx = blockIdx.x % gn;
    const int by = blockIdx.x / gn;
    const int tid = threadIdx.x;
    const int tx = tid & 15;
    const int ty = tid >> 4;
    const int row0 = by * BM;
    const int col0 = bx * BN;

    float acc[4][4] = {};

    for (int k0 = 0; k0 < K; k0 += BK) {
#pragma unroll
        for (int i = 0; i < 4; ++i) {
            int idx = tid + i * 256;
            int r = idx >> 4, k = idx & 15;
            int gr = row0 + r;
            float v = (gr < M) ? A[(size_t)gr * K + k0 + k] : 0.0f;
            if (RELU_A) v = fmaxf(v, 0.0f);
            As[k][r] = v;
        }
#pragma unroll
        for (int i = 0; i < 4; ++i) {
            int idx = tid + i * 256;
            if (!WT) {
                int k = idx >> 6, n = idx & 63;
                Ws[k][n] = W[(size_t)(k0 + k) * N + col0 + n];
            } else {
                int n = idx >> 4, k = idx & 15;
                Ws[k][n] = W[(size_t)(col0 + n) * K + k0 + k];
            }
        }
        __syncthreads();

#pragma unroll
        for (int kk = 0; kk < BK; ++kk) {
            float a[4], w[4];
#pragma unroll
            for (int i = 0; i < 4; ++i) a[i] = As[kk][ty * 4 + i];
#pragma unroll
            for (int j = 0; j < 4; ++j) w[j] = Ws[kk][tx * 4 + j];
#pragma unroll
            for (int i = 0; i < 4; ++i)
#pragma unroll
                for (int j = 0; j < 4; ++j) acc[i][j] += a[i] * w[j];
        }
        __syncthreads();
    }

#pragma unroll
    for (int i = 0; i < 4; ++i) {
        int gr = row0 + ty * 4 + i;
        if (gr >= M) continue;
#pragma unroll
        for (int j = 0; j < 4; ++j) {
            int gc = col0 + tx * 4 + j;
            float v = acc[i][j];
            if (bias) v += bias[gc];
            C[(size_t)gr * N + gc] = (unsigned short)f2bf(v);
        }
    }
}

// ---------------------------------------------------------------------------
// shared MFMA helpers (128x128 tiles, XOR-swizzled LDS, 4 waves)
// ---------------------------------------------------------------------------
static __device__ __forceinline__ void mfma_pass(const short* __restrict__ S,
                                                 const short* __restrict__ Wsh,
                                                 int r0, int c0, int lrow, int lk,
                                                 f32x4 acc[4][4]) {
#pragma unroll
    for (int ks = 0; ks < 4; ++ks) {
        int chunk = (ks << 2) + lk;
        bf16x8 a[4], b[4];
#pragma unroll
        for (int m = 0; m < 4; ++m) {
            int rr = r0 + (m << 4) + lrow;
            a[m] = *(const bf16x8*)&S[rr * 128 + ((chunk ^ (rr & 7)) << 3)];
        }
#pragma unroll
        for (int n = 0; n < 4; ++n) {
            int cc = c0 + (n << 4) + lrow;
            b[n] = *(const bf16x8*)&Wsh[cc * 128 + ((chunk ^ (cc & 7)) << 3)];
        }
#pragma unroll
        for (int m = 0; m < 4; ++m)
#pragma unroll
            for (int n = 0; n < 4; ++n)
                acc[m][n] = __builtin_amdgcn_mfma_f32_16x16x32_bf16(a[m], b[n], acc[m][n], 0, 0, 0);
    }
}

static __device__ __forceinline__ void stage_w(const short* __restrict__ Wt, int gate,
                                               short* __restrict__ Wsh, int tid) {
#pragma unroll
    for (int i = 0; i < 8; ++i) {
        int chunk = tid + (i << 8);
        int r = chunk >> 4, c = chunk & 15;
        bf16x8 v = *(const bf16x8*)&Wt[(((size_t)((gate << 7) + r)) << 7) + (c << 3)];
        *(bf16x8*)&Wsh[r * 128 + ((c ^ (r & 7)) << 3)] = v;
    }
}

// ---------------------------------------------------------------------------
// bf16 MFMA GEMM (convs): C = relu?(A) @ Wt^T, bf16 out. K=N=128.
// ---------------------------------------------------------------------------
template <bool RELU_A>
__global__ __launch_bounds__(256) void gemm_mfma_k(const unsigned short* __restrict__ A,
                                                   const short* __restrict__ Wt,
                                                   unsigned short* __restrict__ C,
                                                   int M) {
    __shared__ short As[128 * 128];
    __shared__ short Bs[128 * 128];

    const int row0 = blockIdx.x << 7;
    const int tid = threadIdx.x;

#pragma unroll
    for (int i = 0; i < 8; ++i) {
        int chunk = tid + (i << 8);
        int r = chunk >> 4, c = chunk & 15;
        int gr = row0 + r;
        bf16x8 t;
        if (gr < M) {
            t = *(const bf16x8*)(A + (((size_t)gr) << 7) + (c << 3));
            if (RELU_A) {
#pragma unroll
                for (int j = 0; j < 8; ++j) {
                    unsigned short u = (unsigned short)t[j];
                    t[j] = (short)((u & 0x8000u) ? 0 : u);
                }
            }
        } else {
#pragma unroll
            for (int j = 0; j < 8; ++j) t[j] = 0;
        }
        *(bf16x8*)&As[r * 128 + ((c ^ (r & 7)) << 3)] = t;
    }
    stage_w(Wt, 0, Bs, tid);
    __syncthreads();

    const int lane = tid & 63;
    const int wid = tid >> 6;
    const int r0 = (wid >> 1) << 6;
    const int c0 = (wid & 1) << 6;
    const int lrow = lane & 15;
    const int lk = lane >> 4;

    f32x4 acc[4][4] = {};
    mfma_pass(As, Bs, r0, c0, lrow, lk, acc);

#pragma unroll
    for (int n = 0; n < 4; ++n) {
        int gc = c0 + (n << 4) + lrow;
#pragma unroll
        for (int m = 0; m < 4; ++m) {
#pragma unroll
            for (int j = 0; j < 4; ++j) {
                int gr = row0 + r0 + (m << 4) + (lk << 2) + j;
                if (gr < M)
                    C[((size_t)gr << 7) + gc] = (unsigned short)f2bf(acc[m][n][j]);
            }
        }
    }
}

// ---------------------------------------------------------------------------
// Fused GRU: per 128-row block, computes all six gate GEMMs (K=128 each)
// with staged weight tiles, gate math in registers, h' written directly.
//   gi = A@Wih^T + bih ; gh = h@Whh^T + bhh
//   r = s(gi_r+gh_r); z = s(gi_z+gh_z); n = tanh(gi_n + r*gh_n)
//   h' = (1-z)*n + z*h   (h read fp32 from global in epilogue)
// ---------------------------------------------------------------------------
template <bool RELU_A>
__global__ __launch_bounds__(256, 1) void gru_fused_k(const unsigned short* __restrict__ A,
                                                      const unsigned short* __restrict__ hb,
                                                      const float* __restrict__ h32,
                                                      const short* __restrict__ WihT,
                                                      const short* __restrict__ WhhT,
                                                      const float* __restrict__ bih,
                                                      const float* __restrict__ bhh,
                                                      float* __restrict__ hn,
                                                      unsigned short* __restrict__ hnb,
                                                      int M) {
    __shared__ short As[128 * 128];
    __shared__ short Hs[128 * 128];
    __shared__ short Wsh[128 * 128];

    const int row0 = blockIdx.x << 7;
    const int tid = threadIdx.x;

    // stage A (relu optional) and h tiles
#pragma unroll
    for (int i = 0; i < 8; ++i) {
        int chunk = tid + (i << 8);
        int r = chunk >> 4, c = chunk & 15;
        int gr = row0 + r;
        bf16x8 ta, th;
        if (gr < M) {
            ta = *(const bf16x8*)(A + (((size_t)gr) << 7) + (c << 3));
            if (RELU_A) {
#pragma unroll
                for (int j = 0; j < 8; ++j) {
                    unsigned short u = (unsigned short)ta[j];
                    ta[j] = (short)((u & 0x8000u) ? 0 : u);
                }
            }
            th = *(const bf16x8*)(hb + (((size_t)gr) << 7) + (c << 3));
        } else {
#pragma unroll
            for (int j = 0; j < 8; ++j) { ta[j] = 0; th[j] = 0; }
        }
        int sw = r * 128 + ((c ^ (r & 7)) << 3);
        *(bf16x8*)&As[sw] = ta;
        *(bf16x8*)&Hs[sw] = th;
    }

    const int lane = tid & 63;
    const int wid = tid >> 6;
    const int r0 = (wid >> 1) << 6;
    const int c0 = (wid & 1) << 6;
    const int lrow = lane & 15;
    const int lk = lane >> 4;

    f32x4 accR[4][4] = {};
    f32x4 accNh[4][4] = {};
    f32x4 accNi[4][4] = {};
    f32x4 accZ[4][4] = {};

    // pass 1: gi_r (A @ Wih_r)
    stage_w(WihT, 0, Wsh, tid);
    __syncthreads();
    mfma_pass(As, Wsh, r0, c0, lrow, lk, accR);
    __syncthreads();
    // pass 2: += gh_r (h @ Whh_r)
    stage_w(WhhT, 0, Wsh, tid);
    __syncthreads();
    mfma_pass(Hs, Wsh, r0, c0, lrow, lk, accR);
    __syncthreads();
    // pass 3: gh_n
    stage_w(WhhT, 2, Wsh, tid);
    __syncthreads();
    mfma_pass(Hs, Wsh, r0, c0, lrow, lk, accNh);
    __syncthreads();
    // pass 4: gi_n
    stage_w(WihT, 2, Wsh, tid);
    __syncthreads();
    mfma_pass(As, Wsh, r0, c0, lrow, lk, accNi);
    __syncthreads();

    // biases for this lane's columns
    float br[4], bz[4], bni[4], bnh[4];
#pragma unroll
    for (int n = 0; n < 4; ++n) {
        int gc = c0 + (n << 4) + lrow;
        br[n] = bih[gc] + bhh[gc];
        bz[n] = bih[128 + gc] + bhh[128 + gc];
        bni[n] = bih[256 + gc];
        bnh[n] = bhh[256 + gc];
    }

    // fold r and n: accNh <- n = tanh(gi_n + r*gh_n); frees accR/accNi
#pragma unroll
    for (int m = 0; m < 4; ++m)
#pragma unroll
        for (int n = 0; n < 4; ++n)
#pragma unroll
            for (int j = 0; j < 4; ++j) {
                float rr = sigmoidf_(accR[m][n][j] + br[n]);
                accNh[m][n][j] = tanhf(accNi[m][n][j] + bni[n] +
                                       rr * (accNh[m][n][j] + bnh[n]));
            }

    // pass 5: gi_z
    stage_w(WihT, 1, Wsh, tid);
    __syncthreads();
    mfma_pass(As, Wsh, r0, c0, lrow, lk, accZ);
    __syncthreads();
    // pass 6: += gh_z
    stage_w(WhhT, 1, Wsh, tid);
    __syncthreads();
    mfma_pass(Hs, Wsh, r0, c0, lrow, lk, accZ);

    // epilogue: z, h' = (1-z)*n + z*h
#pragma unroll
    for (int m = 0; m < 4; ++m)
#pragma unroll
        for (int n = 0; n < 4; ++n)
#pragma unroll
            for (int j = 0; j < 4; ++j) {
                int grow = row0 + r0 + (m << 4) + (lk << 2) + j;
                if (grow >= M) continue;
                int gcol = c0 + (n << 4) + lrow;
                float zz = sigmoidf_(accZ[m][n][j] + bz[n]);
                float hv = h32[((size_t)grow << 7) + gcol];
                float v = (1.0f - zz) * accNh[m][n][j] + zz * hv;
                hn[((size_t)grow << 7) + gcol] = v;
                hnb[((size_t)grow << 7) + gcol] = (unsigned short)f2bf(v);
            }
}

// ---------------------------------------------------------------------------
// GCN gather (pull): one wave per destination node, bf16 HW rows.
// out[d] = dd*(dd*HW[d] + sum_e dis[s_e]*HW[s_e]) + bias   (bf16 out)
// ---------------------------------------------------------------------------
__global__ __launch_bounds__(256) void gcn_gather_k(const unsigned short* __restrict__ HW,
                                                    const float* __restrict__ dis,
                                                    const int* __restrict__ rowptr,
                                                    const int* __restrict__ csr_src,
                                                    const float* __restrict__ bias,
                                                    unsigned short* __restrict__ out, int N) {
    int node = (blockIdx.x * 256 + threadIdx.x) >> 6;
    int lane = threadIdx.x & 63;
    if (node >= N) return;
    float dd = dis[node];
    unsigned v0 = *(const unsigned*)&HW[((size_t)node << HBITS) + (lane << 1)];
    float2 b2 = *(const float2*)&bias[lane << 1];
    float accx = bf2f((unsigned short)(v0 & 0xFFFFu)) * dd;
    float accy = bf2f((unsigned short)(v0 >> 16)) * dd;
    int e = rowptr[node], end = rowptr[node + 1];
    for (; e + 1 < end; e += 2) {
        int s0 = csr_src[e], s1 = csr_src[e + 1];
        float w0 = dis[s0], w1 = dis[s1];
        unsigned a = *(const unsigned*)&HW[((size_t)s0 << HBITS) + (lane << 1)];
        unsigned b = *(const unsigned*)&HW[((size_t)s1 << HBITS) + (lane << 1)];
        accx += bf2f((unsigned short)(a & 0xFFFFu)) * w0;
        accy += bf2f((unsigned short)(a >> 16)) * w0;
        accx += bf2f((unsigned short)(b & 0xFFFFu)) * w1;
        accy += bf2f((unsigned short)(b >> 16)) * w1;
    }
    if (e < end) {
        int s = csr_src[e];
        float w = dis[s];
        unsigned a = *(const unsigned*)&HW[((size_t)s << HBITS) + (lane << 1)];
        accx += bf2f((unsigned short)(a & 0xFFFFu)) * w;
        accy += bf2f((unsigned short)(a >> 16)) * w;
    }
    accx = accx * dd + b2.x;
    accy = accy * dd + b2.y;
    unsigned o = ((unsigned)(unsigned short)f2bf(accy) << 16) | (unsigned short)f2bf(accx);
    *(unsigned*)&out[((size_t)node << HBITS) + (lane << 1)] = o;
}

// ---------------------------------------------------------------------------
// Output head
// ---------------------------------------------------------------------------
#define OUT_DIM 5
__global__ void out_softmax_k(const float* __restrict__ h, const float* __restrict__ Wo,
                              const float* __restrict__ bo, float* __restrict__ out, int N) {
    int gtid = blockIdx.x * blockDim.x + threadIdx.x;
    int node = gtid >> 6;
    int lane = threadIdx.x & 63;
    if (node >= N) return;
    const float* hr = h + ((size_t)node << HBITS);
    float h0 = hr[lane];
    float h1 = hr[lane + 64];
    float acc[OUT_DIM];
#pragma unroll
    for (int o = 0; o < OUT_DIM; ++o)
        acc[o] = h0 * Wo[lane * OUT_DIM + o] + h1 * Wo[(lane + 64) * OUT_DIM + o];
#pragma unroll
    for (int off = 32; off >= 1; off >>= 1) {
#pragma unroll
        for (int o = 0; o < OUT_DIM; ++o) acc[o] += __shfl_down(acc[o], off, 64);
    }
    if (lane == 0) {
        float v[OUT_DIM], m = -1e30f;
#pragma unroll
        for (int o = 0; o < OUT_DIM; ++o) { v[o] = acc[o] + bo[o]; m = fmaxf(m, v[o]); }
        float s = 0.0f;
#pragma unroll
        for (int o = 0; o < OUT_DIM; ++o) { v[o] = expf(v[o] - m); s += v[o]; }
        float inv = 1.0f / s;
#pragma unroll
        for (int o = 0; o < OUT_DIM; ++o) out[(size_t)node * OUT_DIM + o] = v[o] * inv;
    }
}

// ---------------------------------------------------------------------------
// launch
// ---------------------------------------------------------------------------
static inline int cdiv(long long a, long long b) { return (int)((a + b - 1) / b); }
static inline char* align256(char* p) {
    return (char*)(((uintptr_t)p + 255) & ~(uintptr_t)255);
}

extern "C" void kernel_launch(void* const* d_in, const int* in_sizes, int n_in,
                              void* d_out, int out_size, void* d_ws, size_t ws_size,
                              hipStream_t stream) {
    const float* x       = (const float*)d_in[0];
    const int*   eidx    = (const int*)d_in[1];
    const float* proj_W  = (const float*)d_in[2];
    const float* proj_b  = (const float*)d_in[3];
    const float* conv1_W = (const float*)d_in[4];
    const float* conv1_b = (const float*)d_in[5];
    const float* conv2_W = (const float*)d_in[6];
    const float* conv2_b = (const float*)d_in[7];
    const float* hidden_c= (const float*)d_in[8];
    const float* gru_Wih = (const float*)d_in[9];
    const float* gru_Whh = (const float*)d_in[10];
    const float* gru_bih = (const float*)d_in[11];
    const float* gru_bhh = (const float*)d_in[12];
    const float* out_W   = (const float*)d_in[13];
    const float* out_b   = (const float*)d_in[14];
    float* out = (float*)d_out;

    const int F = 16, H = 128, G3 = 384;
    const int N = in_sizes[0] / F;
    const int E = in_sizes[1] / 2;
    const int* src = eidx;
    const int* dst = eidx + E;

    const int TPB = 256;
    const int nScanBlocks = cdiv(N, 256);

    // workspace (256B-aligned slots)
    char* wp = (char*)d_ws;
#define ALLOC(ptr_t, name, bytes) ptr_t name = (ptr_t)wp; wp = align256(wp + (bytes))
    ALLOC(int*, cnt, (size_t)N * 4);
    ALLOC(int*, rowptr, (size_t)(N + 1) * 4);
    ALLOC(int*, pos, (size_t)N * 4);
    ALLOC(int*, bsum, 256 * 4);
    ALLOC(int*, csr_src, (size_t)E * 4);
    ALLOC(float*, dis, (size_t)N * 4);
    ALLOC(short*, c1Wt, (size_t)H * H * 2);
    ALLOC(short*, c2Wt, (size_t)H * H * 2);
    ALLOC(short*, WihT, (size_t)G3 * H * 2);
    ALLOC(short*, WhhT, (size_t)G3 * H * 2);
    ALLOC(float*, h0, (size_t)N * H * 4);
    ALLOC(float*, h1, (size_t)N * H * 4);
    ALLOC(unsigned short*, h0b, (size_t)N * H * 2);
    ALLOC(unsigned short*, h1b, (size_t)N * H * 2);
    ALLOC(unsigned short*, Abuf, (size_t)N * H * 2);
    ALLOC(unsigned short*, HWb, (size_t)N * H * 2);
#undef ALLOC

    const int totNH = N * H;

    // --- weight preconversion (bf16, [n][k]) ---
    cvt_bf16_t_k<<<cdiv(H * H, TPB), TPB, 0, stream>>>(conv1_W, c1Wt, H, H);
    cvt_bf16_t_k<<<cdiv(H * H, TPB), TPB, 0, stream>>>(conv2_W, c2Wt, H, H);
    cvt_bf16_k<<<cdiv(G3 * H, TPB), TPB, 0, stream>>>(gru_Wih, WihT, G3 * H);
    cvt_bf16_k<<<cdiv(G3 * H, TPB), TPB, 0, stream>>>(gru_Whh, WhhT, G3 * H);

    // --- CSR build + normalization ---
    zero_cnt_k<<<cdiv(N, TPB), TPB, 0, stream>>>(cnt, N);
    count_k<<<cdiv(E, TPB), TPB, 0, stream>>>(dst, cnt, E);
    scan1_k<<<nScanBlocks, 256, 0, stream>>>(cnt, rowptr, bsum, N);
    scan2_k<<<1, 256, 0, stream>>>(bsum, nScanBlocks);
    scan3_k<<<nScanBlocks, 256, 0, stream>>>(rowptr, bsum, cnt, pos, dis, N, E);
    reorder_k<<<cdiv(E, TPB), TPB, 0, stream>>>(src, dst, pos, csr_src, E);

    // --- h init ---
    h_init_k<<<cdiv(totNH, TPB), TPB, 0, stream>>>(hidden_c, h0, h0b, totNH);

    float* h_cur = h0;            float* h_nxt = h1;
    unsigned short* hb_cur = h0b; unsigned short* hb_nxt = h1b;

    const int gmM = cdiv(N, 128);
    const int gatherBlocks = cdiv((long long)N * 64, TPB);

    // --- proj (K=16, fp32 path, bf16 out) ---
    dim3 gridP(cdiv(N, BM) * (H / BN));
    gemm_k<false, false><<<gridP, TPB, 0, stream>>>(x, proj_W, proj_b, Abuf, N, F, H);

    // --- GRU step 0 (fused) ---
    gru_fused_k<false><<<gmM, TPB, 0, stream>>>(Abuf, hb_cur, h_cur, WihT, WhhT,
                                                gru_bih, gru_bhh, h_nxt, hb_nxt, N);
    { float* t = h_cur; h_cur = h_nxt; h_nxt = t; }
    { unsigned short* t = hb_cur; hb_cur = hb_nxt; hb_nxt = t; }

    for (int it = 0; it < 3; ++it) {
        gemm_mfma_k<false><<<gmM, TPB, 0, stream>>>(hb_cur, c1Wt, HWb, N);
        gcn_gather_k<<<gatherBlocks, TPB, 0, stream>>>(HWb, dis, rowptr, csr_src,
                                                       conv1_b, Abuf, N);
        gemm_mfma_k<true><<<gmM, TPB, 0, stream>>>(Abuf, c2Wt, HWb, N);
        gcn_gather_k<<<gatherBlocks, TPB, 0, stream>>>(HWb, dis, rowptr, csr_src,
                                                       conv2_b, Abuf, N);
        gru_fused_k<true><<<gmM, TPB, 0, stream>>>(Abuf, hb_cur, h_cur, WihT, WhhT,
                                                   gru_bih, gru_bhh, h_nxt, hb_nxt, N);
        { float* t = h_cur; h_cur = h_nxt; h_nxt = t; }
        { unsigned short* t = hb_cur; hb_cur = hb_nxt; hb_nxt = t; }
    }

    // --- output head ---
    out_softmax_k<<<cdiv((long long)N * 64, TPB), TPB, 0, stream>>>(h_cur, out_W, out_b, out, N);
}

// Round 6
// 775.407 us; speedup vs baseline: 4.5809x; 1.0798x over previous
//
#include <hip/hip_runtime.h>
#include <hip/hip_bf16.h>

#define NODES_H 128
#define HBITS 7   // 128 = 1<<7

typedef __attribute__((ext_vector_type(8))) short bf16x8;
typedef __attribute__((ext_vector_type(4))) float f32x4;

static __device__ __forceinline__ short f2bf(float f) {
    union { float f; unsigned u; } v; v.f = f;
    unsigned r = v.u + 0x7FFFu + ((v.u >> 16) & 1u);  // RNE
    return (short)(r >> 16);
}
static __device__ __forceinline__ float bf2f(unsigned short u) {
    union { unsigned u; float f; } v; v.u = ((unsigned)u) << 16;
    return v.f;
}
static __device__ __forceinline__ float sigmoidf_(float x) {
    return 1.0f / (1.0f + expf(-x));
}

// ---------------------------------------------------------------------------
// weight preconversion
// ---------------------------------------------------------------------------
__global__ void cvt_bf16_k(const float* __restrict__ in, short* __restrict__ out, int n) {
    int i = blockIdx.x * blockDim.x + threadIdx.x;
    if (i < n) out[i] = f2bf(in[i]);
}

__global__ void cvt_bf16_t_k(const float* __restrict__ in, short* __restrict__ out, int K, int N) {
    int i = blockIdx.x * blockDim.x + threadIdx.x;
    if (i >= K * N) return;
    int nn = i >> HBITS;
    int kk = i & (NODES_H - 1);
    out[i] = f2bf(in[kk * N + nn]);  // out[n][k] = in[k][n], K==128
}

// ---------------------------------------------------------------------------
// CSR build
// ---------------------------------------------------------------------------
__global__ void zero_cnt_k(int* __restrict__ cnt, int N) {
    int i = blockIdx.x * blockDim.x + threadIdx.x;
    if (i < N) cnt[i] = 0;
}

__global__ void count_k(const int* __restrict__ dst, int* __restrict__ cnt, int E) {
    int e = blockIdx.x * blockDim.x + threadIdx.x;
    if (e < E) atomicAdd(&cnt[dst[e]], 1);
}

__global__ __launch_bounds__(256) void scan1_k(const int* __restrict__ cnt,
                                               int* __restrict__ rowptr,
                                               int* __restrict__ bsum, int N) {
    __shared__ int buf[256];
    int tid = threadIdx.x;
    int i = blockIdx.x * 256 + tid;
    int v = (i < N) ? cnt[i] : 0;
    buf[tid] = v;
    __syncthreads();
#pragma unroll
    for (int off = 1; off < 256; off <<= 1) {
        int t = (tid >= off) ? buf[tid - off] : 0;
        __syncthreads();
        buf[tid] += t;
        __syncthreads();
    }
    if (i < N) rowptr[i] = buf[tid] - v;
    if (tid == 255) bsum[blockIdx.x] = buf[255];
}

__global__ __launch_bounds__(256) void scan2_k(int* __restrict__ bsum, int nb) {
    __shared__ int buf[256];
    int tid = threadIdx.x;
    int v = (tid < nb) ? bsum[tid] : 0;
    buf[tid] = v;
    __syncthreads();
#pragma unroll
    for (int off = 1; off < 256; off <<= 1) {
        int t = (tid >= off) ? buf[tid - off] : 0;
        __syncthreads();
        buf[tid] += t;
        __syncthreads();
    }
    if (tid < nb) bsum[tid] = buf[tid] - v;
}

__global__ void scan3_k(int* __restrict__ rowptr, const int* __restrict__ bsum,
                        const int* __restrict__ cnt, int* __restrict__ pos,
                        float* __restrict__ dis, int N, int E) {
    int i = blockIdx.x * blockDim.x + threadIdx.x;
    if (i < N) {
        int v = rowptr[i] + bsum[blockIdx.x];
        rowptr[i] = v;
        pos[i] = v;
        dis[i] = rsqrtf((float)(cnt[i] + 1));
    }
    if (i == 0) rowptr[N] = E;
}

__global__ void reorder_k(const int* __restrict__ src, const int* __restrict__ dst,
                          int* __restrict__ pos, int* __restrict__ csr_src, int E) {
    int e = blockIdx.x * blockDim.x + threadIdx.x;
    if (e >= E) return;
    int p = atomicAdd(&pos[dst[e]], 1);
    csr_src[p] = src[e];
}

// ---------------------------------------------------------------------------
// h init (bf16 state only)
// ---------------------------------------------------------------------------
__global__ void h_init_k(const float* __restrict__ hc, unsigned short* __restrict__ hb,
                         int total) {
    int i = blockIdx.x * blockDim.x + threadIdx.x;
    if (i < total) hb[i] = (unsigned short)f2bf(hc[i & (NODES_H - 1)]);
}

// ---------------------------------------------------------------------------
// fp32 tiled GEMM (proj: K=16), bf16 output
// ---------------------------------------------------------------------------
#define BM 64
#define BN 64
#define BK 16

template <bool WT, bool RELU_A>
__global__ __launch_bounds__(256) void gemm_k(const float* __restrict__ A,
                                              const float* __restrict__ W,
                                              const float* __restrict__ bias,
                                              unsigned short* __restrict__ C,
                                              int M, int K, int N) {
    __shared__ float As[BK][BM + 1];
    __shared__ float Ws[BK][BN + 1];

    const int gn = N / BN;
    const int bx = blockIdx.x % gn;
    const int by = blockIdx.x / gn;
    const int tid = threadIdx.x;
    const int tx = tid & 15;
    const int ty = tid >> 4;
    const int row0 = by * BM;
    const int col0 = bx * BN;

    float acc[4][4] = {};

    for (int k0 = 0; k0 < K; k0 += BK) {
#pragma unroll
        for (int i = 0; i < 4; ++i) {
            int idx = tid + i * 256;
            int r = idx >> 4, k = idx & 15;
            int gr = row0 + r;
            float v = (gr < M) ? A[(size_t)gr * K + k0 + k] : 0.0f;
            if (RELU_A) v = fmaxf(v, 0.0f);
            As[k][r] = v;
        }
#pragma unroll
        for (int i = 0; i < 4; ++i) {
            int idx = tid + i * 256;
            if (!WT) {
                int k = idx >> 6, n = idx & 63;
                Ws[k][n] = W[(size_t)(k0 + k) * N + col0 + n];
            } else {
                int n = idx >> 4, k = idx & 15;
                Ws[k][n] = W[(size_t)(col0 + n) * K + k0 + k];
            }
        }
        __syncthreads();

#pragma unroll
        for (int kk = 0; kk < BK; ++kk) {
            float a[4], w[4];
#pragma unroll
            for (int i = 0; i < 4; ++i) a[i] = As[kk][ty * 4 + i];
#pragma unroll
            for (int j = 0; j < 4; ++j) w[j] = Ws[kk][tx * 4 + j];
#pragma unroll
            for (int i = 0; i < 4; ++i)
#pragma unroll
                for (int j = 0; j < 4; ++j) acc[i][j] += a[i] * w[j];
        }
        __syncthreads();
    }

#pragma unroll
    for (int i = 0; i < 4; ++i) {
        int gr = row0 + ty * 4 + i;
        if (gr >= M) continue;
#pragma unroll
        for (int j = 0; j < 4; ++j) {
            int gc = col0 + tx * 4 + j;
            float v = acc[i][j];
            if (bias) v += bias[gc];
            C[(size_t)gr * N + gc] = (unsigned short)f2bf(v);
        }
    }
}

// ---------------------------------------------------------------------------
// MFMA pass: A from swizzled LDS, B fragments straight from global (L2-hot
// weights, [128][128] bf16 k-contiguous). No barriers inside.
// ---------------------------------------------------------------------------
static __device__ __forceinline__ void mfma_pass_g(const short* __restrict__ S,
                                                   const short* __restrict__ Wg,
                                                   int r0, int c0, int lrow, int lk,
                                                   f32x4 acc[4][4]) {
#pragma unroll
    for (int ks = 0; ks < 4; ++ks) {
        int chunk = (ks << 2) + lk;
        bf16x8 a[4], b[4];
#pragma unroll
        for (int m = 0; m < 4; ++m) {
            int rr = r0 + (m << 4) + lrow;
            a[m] = *(const bf16x8*)&S[rr * 128 + ((chunk ^ (rr & 7)) << 3)];
        }
#pragma unroll
        for (int n = 0; n < 4; ++n) {
            int cc = c0 + (n << 4) + lrow;
            b[n] = *(const bf16x8*)&Wg[((size_t)cc << 7) + (chunk << 3)];
        }
#pragma unroll
        for (int m = 0; m < 4; ++m)
#pragma unroll
            for (int n = 0; n < 4; ++n)
                acc[m][n] = __builtin_amdgcn_mfma_f32_16x16x32_bf16(a[m], b[n], acc[m][n], 0, 0, 0);
    }
}

// ---------------------------------------------------------------------------
// bf16 MFMA GEMM (convs): C = relu?(A) @ Wt^T, bf16 out. K=N=128.
// A staged in 32KB LDS, W from global. One barrier.
// ---------------------------------------------------------------------------
template <bool RELU_A>
__global__ __launch_bounds__(256, 3) void gemm_mfma_k(const unsigned short* __restrict__ A,
                                                      const short* __restrict__ Wt,
                                                      unsigned short* __restrict__ C,
                                                      int M) {
    __shared__ short As[128 * 128];

    const int row0 = blockIdx.x << 7;
    const int tid = threadIdx.x;

#pragma unroll
    for (int i = 0; i < 8; ++i) {
        int chunk = tid + (i << 8);
        int r = chunk >> 4, c = chunk & 15;
        int gr = row0 + r;
        bf16x8 t;
        if (gr < M) {
            t = *(const bf16x8*)(A + (((size_t)gr) << 7) + (c << 3));
            if (RELU_A) {
#pragma unroll
                for (int j = 0; j < 8; ++j) {
                    unsigned short u = (unsigned short)t[j];
                    t[j] = (short)((u & 0x8000u) ? 0 : u);
                }
            }
        } else {
#pragma unroll
            for (int j = 0; j < 8; ++j) t[j] = 0;
        }
        *(bf16x8*)&As[r * 128 + ((c ^ (r & 7)) << 3)] = t;
    }
    __syncthreads();

    const int lane = tid & 63;
    const int wid = tid >> 6;
    const int r0 = (wid >> 1) << 6;
    const int c0 = (wid & 1) << 6;
    const int lrow = lane & 15;
    const int lk = lane >> 4;

    f32x4 acc[4][4] = {};
    mfma_pass_g(As, Wt, r0, c0, lrow, lk, acc);

#pragma unroll
    for (int n = 0; n < 4; ++n) {
        int gc = c0 + (n << 4) + lrow;
#pragma unroll
        for (int m = 0; m < 4; ++m) {
#pragma unroll
            for (int j = 0; j < 4; ++j) {
                int gr = row0 + r0 + (m << 4) + (lk << 2) + j;
                if (gr < M)
                    C[((size_t)gr << 7) + gc] = (unsigned short)f2bf(acc[m][n][j]);
            }
        }
    }
}

// ---------------------------------------------------------------------------
// Fused GRU: six gate GEMMs per 128-row block, weights from global (L2),
// A/h tiles in 64KB LDS, ONE barrier, gate math in registers.
//   r = s(gi_r+gh_r); accT = r*(gh_n + bnh); accT += gi_n (MFMA C-in);
//   n = tanh(accT + bni); z = s(gi_z+gh_z); h' = (1-z)*n + z*h  (h = bf16)
// ---------------------------------------------------------------------------
template <bool RELU_A>
__global__ __launch_bounds__(256, 2) void gru_fused_k(const unsigned short* __restrict__ A,
                                                      const unsigned short* __restrict__ hb,
                                                      const short* __restrict__ WihT,
                                                      const short* __restrict__ WhhT,
                                                      const float* __restrict__ bih,
                                                      const float* __restrict__ bhh,
                                                      unsigned short* __restrict__ hnb,
                                                      int M) {
    __shared__ short As[128 * 128];
    __shared__ short Hs[128 * 128];

    const int row0 = blockIdx.x << 7;
    const int tid = threadIdx.x;

    // stage A (relu optional) and h tiles
#pragma unroll
    for (int i = 0; i < 8; ++i) {
        int chunk = tid + (i << 8);
        int r = chunk >> 4, c = chunk & 15;
        int gr = row0 + r;
        bf16x8 ta, th;
        if (gr < M) {
            ta = *(const bf16x8*)(A + (((size_t)gr) << 7) + (c << 3));
            if (RELU_A) {
#pragma unroll
                for (int j = 0; j < 8; ++j) {
                    unsigned short u = (unsigned short)ta[j];
                    ta[j] = (short)((u & 0x8000u) ? 0 : u);
                }
            }
            th = *(const bf16x8*)(hb + (((size_t)gr) << 7) + (c << 3));
        } else {
#pragma unroll
            for (int j = 0; j < 8; ++j) { ta[j] = 0; th[j] = 0; }
        }
        int sw = r * 128 + ((c ^ (r & 7)) << 3);
        *(bf16x8*)&As[sw] = ta;
        *(bf16x8*)&Hs[sw] = th;
    }
    __syncthreads();

    const int lane = tid & 63;
    const int wid = tid >> 6;
    const int r0 = (wid >> 1) << 6;
    const int c0 = (wid & 1) << 6;
    const int lrow = lane & 15;
    const int lk = lane >> 4;

    // biases for this lane's columns
    float br[4], bz[4], bni[4], bnh[4];
#pragma unroll
    for (int n = 0; n < 4; ++n) {
        int gc = c0 + (n << 4) + lrow;
        br[n] = bih[gc] + bhh[gc];
        bz[n] = bih[128 + gc] + bhh[128 + gc];
        bni[n] = bih[256 + gc];
        bnh[n] = bhh[256 + gc];
    }

    const int GS = 128 * 128;  // per-gate weight stride

    f32x4 accR[4][4] = {};
    f32x4 accT[4][4] = {};

    mfma_pass_g(As, WihT, r0, c0, lrow, lk, accR);           // gi_r
    mfma_pass_g(Hs, WhhT, r0, c0, lrow, lk, accR);           // + gh_r
    mfma_pass_g(Hs, WhhT + 2 * GS, r0, c0, lrow, lk, accT);  // gh_n

    // fold: accT = r * (gh_n + bnh)
#pragma unroll
    for (int m = 0; m < 4; ++m)
#pragma unroll
        for (int n = 0; n < 4; ++n)
#pragma unroll
            for (int j = 0; j < 4; ++j) {
                float rr = sigmoidf_(accR[m][n][j] + br[n]);
                accT[m][n][j] = rr * (accT[m][n][j] + bnh[n]);
            }

    mfma_pass_g(As, WihT + 2 * GS, r0, c0, lrow, lk, accT);  // += gi_n

    // n = tanh(accT + bni)
#pragma unroll
    for (int m = 0; m < 4; ++m)
#pragma unroll
        for (int n = 0; n < 4; ++n)
#pragma unroll
            for (int j = 0; j < 4; ++j)
                accT[m][n][j] = tanhf(accT[m][n][j] + bni[n]);

    f32x4 accZ[4][4] = {};
    mfma_pass_g(As, WihT + GS, r0, c0, lrow, lk, accZ);      // gi_z
    mfma_pass_g(Hs, WhhT + GS, r0, c0, lrow, lk, accZ);      // + gh_z

    // epilogue: z, h' = (1-z)*n + z*h
#pragma unroll
    for (int m = 0; m < 4; ++m)
#pragma unroll
        for (int n = 0; n < 4; ++n)
#pragma unroll
            for (int j = 0; j < 4; ++j) {
                int grow = row0 + r0 + (m << 4) + (lk << 2) + j;
                if (grow >= M) continue;
                int gcol = c0 + (n << 4) + lrow;
                float zz = sigmoidf_(accZ[m][n][j] + bz[n]);
                float hv = bf2f(hb[((size_t)grow << 7) + gcol]);
                float v = (1.0f - zz) * accT[m][n][j] + zz * hv;
                hnb[((size_t)grow << 7) + gcol] = (unsigned short)f2bf(v);
            }
}

// ---------------------------------------------------------------------------
// GCN gather (pull): one wave per destination node, bf16 HW rows.
// out[d] = dd*(dd*HW[d] + sum_e dis[s_e]*HW[s_e]) + bias   (bf16 out)
// ---------------------------------------------------------------------------
__global__ __launch_bounds__(256) void gcn_gather_k(const unsigned short* __restrict__ HW,
                                                    const float* __restrict__ dis,
                                                    const int* __restrict__ rowptr,
                                                    const int* __restrict__ csr_src,
                                                    const float* __restrict__ bias,
                                                    unsigned short* __restrict__ out, int N) {
    int node = (blockIdx.x * 256 + threadIdx.x) >> 6;
    int lane = threadIdx.x & 63;
    if (node >= N) return;
    float dd = dis[node];
    unsigned v0 = *(const unsigned*)&HW[((size_t)node << HBITS) + (lane << 1)];
    float2 b2 = *(const float2*)&bias[lane << 1];
    float accx = bf2f((unsigned short)(v0 & 0xFFFFu)) * dd;
    float accy = bf2f((unsigned short)(v0 >> 16)) * dd;
    int e = rowptr[node], end = rowptr[node + 1];
    for (; e + 1 < end; e += 2) {
        int s0 = csr_src[e], s1 = csr_src[e + 1];
        float w0 = dis[s0], w1 = dis[s1];
        unsigned a = *(const unsigned*)&HW[((size_t)s0 << HBITS) + (lane << 1)];
        unsigned b = *(const unsigned*)&HW[((size_t)s1 << HBITS) + (lane << 1)];
        accx += bf2f((unsigned short)(a & 0xFFFFu)) * w0;
        accy += bf2f((unsigned short)(a >> 16)) * w0;
        accx += bf2f((unsigned short)(b & 0xFFFFu)) * w1;
        accy += bf2f((unsigned short)(b >> 16)) * w1;
    }
    if (e < end) {
        int s = csr_src[e];
        float w = dis[s];
        unsigned a = *(const unsigned*)&HW[((size_t)s << HBITS) + (lane << 1)];
        accx += bf2f((unsigned short)(a & 0xFFFFu)) * w;
        accy += bf2f((unsigned short)(a >> 16)) * w;
    }
    accx = accx * dd + b2.x;
    accy = accy * dd + b2.y;
    unsigned o = ((unsigned)(unsigned short)f2bf(accy) << 16) | (unsigned short)f2bf(accx);
    *(unsigned*)&out[((size_t)node << HBITS) + (lane << 1)] = o;
}

// ---------------------------------------------------------------------------
// Output head (bf16 h input)
// ---------------------------------------------------------------------------
#define OUT_DIM 5
__global__ void out_softmax_k(const unsigned short* __restrict__ h,
                              const float* __restrict__ Wo,
                              const float* __restrict__ bo, float* __restrict__ out, int N) {
    int gtid = blockIdx.x * blockDim.x + threadIdx.x;
    int node = gtid >> 6;
    int lane = threadIdx.x & 63;
    if (node >= N) return;
    const unsigned short* hr = h + ((size_t)node << HBITS);
    float h0 = bf2f(hr[lane]);
    float h1 = bf2f(hr[lane + 64]);
    float acc[OUT_DIM];
#pragma unroll
    for (int o = 0; o < OUT_DIM; ++o)
        acc[o] = h0 * Wo[lane * OUT_DIM + o] + h1 * Wo[(lane + 64) * OUT_DIM + o];
#pragma unroll
    for (int off = 32; off >= 1; off >>= 1) {
#pragma unroll
        for (int o = 0; o < OUT_DIM; ++o) acc[o] += __shfl_down(acc[o], off, 64);
    }
    if (lane == 0) {
        float v[OUT_DIM], m = -1e30f;
#pragma unroll
        for (int o = 0; o < OUT_DIM; ++o) { v[o] = acc[o] + bo[o]; m = fmaxf(m, v[o]); }
        float s = 0.0f;
#pragma unroll
        for (int o = 0; o < OUT_DIM; ++o) { v[o] = expf(v[o] - m); s += v[o]; }
        float inv = 1.0f / s;
#pragma unroll
        for (int o = 0; o < OUT_DIM; ++o) out[(size_t)node * OUT_DIM + o] = v[o] * inv;
    }
}

// ---------------------------------------------------------------------------
// launch
// ---------------------------------------------------------------------------
static inline int cdiv(long long a, long long b) { return (int)((a + b - 1) / b); }
static inline char* align256(char* p) {
    return (char*)(((uintptr_t)p + 255) & ~(uintptr_t)255);
}

extern "C" void kernel_launch(void* const* d_in, const int* in_sizes, int n_in,
                              void* d_out, int out_size, void* d_ws, size_t ws_size,
                              hipStream_t stream) {
    const float* x       = (const float*)d_in[0];
    const int*   eidx    = (const int*)d_in[1];
    const float* proj_W  = (const float*)d_in[2];
    const float* proj_b  = (const float*)d_in[3];
    const float* conv1_W = (const float*)d_in[4];
    const float* conv1_b = (const float*)d_in[5];
    const float* conv2_W = (const float*)d_in[6];
    const float* conv2_b = (const float*)d_in[7];
    const float* hidden_c= (const float*)d_in[8];
    const float* gru_Wih = (const float*)d_in[9];
    const float* gru_Whh = (const float*)d_in[10];
    const float* gru_bih = (const float*)d_in[11];
    const float* gru_bhh = (const float*)d_in[12];
    const float* out_W   = (const float*)d_in[13];
    const float* out_b   = (const float*)d_in[14];
    float* out = (float*)d_out;

    const int F = 16, H = 128, G3 = 384;
    const int N = in_sizes[0] / F;
    const int E = in_sizes[1] / 2;
    const int* src = eidx;
    const int* dst = eidx + E;

    const int TPB = 256;
    const int nScanBlocks = cdiv(N, 256);

    // workspace (256B-aligned slots)
    char* wp = (char*)d_ws;
#define ALLOC(ptr_t, name, bytes) ptr_t name = (ptr_t)wp; wp = align256(wp + (bytes))
    ALLOC(int*, cnt, (size_t)N * 4);
    ALLOC(int*, rowptr, (size_t)(N + 1) * 4);
    ALLOC(int*, pos, (size_t)N * 4);
    ALLOC(int*, bsum, 256 * 4);
    ALLOC(int*, csr_src, (size_t)E * 4);
    ALLOC(float*, dis, (size_t)N * 4);
    ALLOC(short*, c1Wt, (size_t)H * H * 2);
    ALLOC(short*, c2Wt, (size_t)H * H * 2);
    ALLOC(short*, WihT, (size_t)G3 * H * 2);
    ALLOC(short*, WhhT, (size_t)G3 * H * 2);
    ALLOC(unsigned short*, h0b, (size_t)N * H * 2);
    ALLOC(unsigned short*, h1b, (size_t)N * H * 2);
    ALLOC(unsigned short*, Abuf, (size_t)N * H * 2);
    ALLOC(unsigned short*, HWb, (size_t)N * H * 2);
#undef ALLOC

    const int totNH = N * H;

    // --- weight preconversion (bf16, [n][k]) ---
    cvt_bf16_t_k<<<cdiv(H * H, TPB), TPB, 0, stream>>>(conv1_W, c1Wt, H, H);
    cvt_bf16_t_k<<<cdiv(H * H, TPB), TPB, 0, stream>>>(conv2_W, c2Wt, H, H);
    cvt_bf16_k<<<cdiv(G3 * H, TPB), TPB, 0, stream>>>(gru_Wih, WihT, G3 * H);
    cvt_bf16_k<<<cdiv(G3 * H, TPB), TPB, 0, stream>>>(gru_Whh, WhhT, G3 * H);

    // --- CSR build + normalization ---
    zero_cnt_k<<<cdiv(N, TPB), TPB, 0, stream>>>(cnt, N);
    count_k<<<cdiv(E, TPB), TPB, 0, stream>>>(dst, cnt, E);
    scan1_k<<<nScanBlocks, 256, 0, stream>>>(cnt, rowptr, bsum, N);
    scan2_k<<<1, 256, 0, stream>>>(bsum, nScanBlocks);
    scan3_k<<<nScanBlocks, 256, 0, stream>>>(rowptr, bsum, cnt, pos, dis, N, E);
    reorder_k<<<cdiv(E, TPB), TPB, 0, stream>>>(src, dst, pos, csr_src, E);

    // --- h init (bf16) ---
    h_init_k<<<cdiv(totNH, TPB), TPB, 0, stream>>>(hidden_c, h0b, totNH);

    unsigned short* hb_cur = h0b;
    unsigned short* hb_nxt = h1b;

    const int gmM = cdiv(N, 128);
    const int gatherBlocks = cdiv((long long)N * 64, TPB);

    // --- proj (K=16, fp32 path, bf16 out) ---
    dim3 gridP(cdiv(N, BM) * (H / BN));
    gemm_k<false, false><<<gridP, TPB, 0, stream>>>(x, proj_W, proj_b, Abuf, N, F, H);

    // --- GRU step 0 (fused) ---
    gru_fused_k<false><<<gmM, TPB, 0, stream>>>(Abuf, hb_cur, WihT, WhhT,
                                                gru_bih, gru_bhh, hb_nxt, N);
    { unsigned short* t = hb_cur; hb_cur = hb_nxt; hb_nxt = t; }

    for (int it = 0; it < 3; ++it) {
        gemm_mfma_k<false><<<gmM, TPB, 0, stream>>>(hb_cur, c1Wt, HWb, N);
        gcn_gather_k<<<gatherBlocks, TPB, 0, stream>>>(HWb, dis, rowptr, csr_src,
                                                       conv1_b, Abuf, N);
        gemm_mfma_k<true><<<gmM, TPB, 0, stream>>>(Abuf, c2Wt, HWb, N);
        gcn_gather_k<<<gatherBlocks, TPB, 0, stream>>>(HWb, dis, rowptr, csr_src,
                                                       conv2_b, Abuf, N);
        gru_fused_k<true><<<gmM, TPB, 0, stream>>>(Abuf, hb_cur, WihT, WhhT,
                                                   gru_bih, gru_bhh, hb_nxt, N);
        { unsigned short* t = hb_cur; hb_cur = hb_nxt; hb_nxt = t; }
    }

    // --- output head ---
    out_softmax_k<<<cdiv((long long)N * 64, TPB), TPB, 0, stream>>>(hb_cur, out_W, out_b, out, N);
}

// Round 7
// 701.672 us; speedup vs baseline: 5.0623x; 1.1051x over previous
//
#include <hip/hip_runtime.h>
#include <hip/hip_bf16.h>

#define NODES_H 128
#define HBITS 7   // 128 = 1<<7

typedef __attribute__((ext_vector_type(8))) short bf16x8;
typedef __attribute__((ext_vector_type(4))) float f32x4;

static __device__ __forceinline__ short f2bf(float f) {
    union { float f; unsigned u; } v; v.f = f;
    unsigned r = v.u + 0x7FFFu + ((v.u >> 16) & 1u);  // RNE
    return (short)(r >> 16);
}
static __device__ __forceinline__ float bf2f(unsigned short u) {
    union { unsigned u; float f; } v; v.u = ((unsigned)u) << 16;
    return v.f;
}
static __device__ __forceinline__ float sigmoidf_(float x) {
    return 1.0f / (1.0f + expf(-x));
}

// ---------------------------------------------------------------------------
// weight preconversion
// ---------------------------------------------------------------------------
__global__ void cvt_bf16_k(const float* __restrict__ in, short* __restrict__ out, int n) {
    int i = blockIdx.x * blockDim.x + threadIdx.x;
    if (i < n) out[i] = f2bf(in[i]);
}

__global__ void cvt_bf16_t_k(const float* __restrict__ in, short* __restrict__ out, int K, int N) {
    int i = blockIdx.x * blockDim.x + threadIdx.x;
    if (i >= K * N) return;
    int nn = i >> HBITS;
    int kk = i & (NODES_H - 1);
    out[i] = f2bf(in[kk * N + nn]);  // out[n][k] = in[k][n], K==128
}

// ---------------------------------------------------------------------------
// CSR build
// ---------------------------------------------------------------------------
__global__ void zero_cnt_k(int* __restrict__ cnt, int N) {
    int i = blockIdx.x * blockDim.x + threadIdx.x;
    if (i < N) cnt[i] = 0;
}

__global__ void count_k(const int* __restrict__ dst, int* __restrict__ cnt, int E) {
    int e = blockIdx.x * blockDim.x + threadIdx.x;
    if (e < E) atomicAdd(&cnt[dst[e]], 1);
}

__global__ __launch_bounds__(256) void scan1_k(const int* __restrict__ cnt,
                                               int* __restrict__ rowptr,
                                               int* __restrict__ bsum, int N) {
    __shared__ int buf[256];
    int tid = threadIdx.x;
    int i = blockIdx.x * 256 + tid;
    int v = (i < N) ? cnt[i] : 0;
    buf[tid] = v;
    __syncthreads();
#pragma unroll
    for (int off = 1; off < 256; off <<= 1) {
        int t = (tid >= off) ? buf[tid - off] : 0;
        __syncthreads();
        buf[tid] += t;
        __syncthreads();
    }
    if (i < N) rowptr[i] = buf[tid] - v;
    if (tid == 255) bsum[blockIdx.x] = buf[255];
}

__global__ __launch_bounds__(256) void scan2_k(int* __restrict__ bsum, int nb) {
    __shared__ int buf[256];
    int tid = threadIdx.x;
    int v = (tid < nb) ? bsum[tid] : 0;
    buf[tid] = v;
    __syncthreads();
#pragma unroll
    for (int off = 1; off < 256; off <<= 1) {
        int t = (tid >= off) ? buf[tid - off] : 0;
        __syncthreads();
        buf[tid] += t;
        __syncthreads();
    }
    if (tid < nb) bsum[tid] = buf[tid] - v;
}

__global__ void scan3_k(int* __restrict__ rowptr, const int* __restrict__ bsum,
                        const int* __restrict__ cnt, int* __restrict__ pos,
                        float* __restrict__ dis, int N, int E) {
    int i = blockIdx.x * blockDim.x + threadIdx.x;
    if (i < N) {
        int v = rowptr[i] + bsum[blockIdx.x];
        rowptr[i] = v;
        pos[i] = v;
        dis[i] = rsqrtf((float)(cnt[i] + 1));
    }
    if (i == 0) rowptr[N] = E;
}

__global__ void reorder_k(const int* __restrict__ src, const int* __restrict__ dst,
                          int* __restrict__ pos, int* __restrict__ csr_src, int E) {
    int e = blockIdx.x * blockDim.x + threadIdx.x;
    if (e >= E) return;
    int p = atomicAdd(&pos[dst[e]], 1);
    csr_src[p] = src[e];
}

// ---------------------------------------------------------------------------
// h init (bf16 state only)
// ---------------------------------------------------------------------------
__global__ void h_init_k(const float* __restrict__ hc, unsigned short* __restrict__ hb,
                         int total) {
    int i = blockIdx.x * blockDim.x + threadIdx.x;
    if (i < total) hb[i] = (unsigned short)f2bf(hc[i & (NODES_H - 1)]);
}

// ---------------------------------------------------------------------------
// fp32 tiled GEMM (proj: K=16), bf16 output
// ---------------------------------------------------------------------------
#define BM 64
#define BN 64
#define BK 16

template <bool WT, bool RELU_A>
__global__ __launch_bounds__(256) void gemm_k(const float* __restrict__ A,
                                              const float* __restrict__ W,
                                              const float* __restrict__ bias,
                                              unsigned short* __restrict__ C,
                                              int M, int K, int N) {
    __shared__ float As[BK][BM + 1];
    __shared__ float Ws[BK][BN + 1];

    const int gn = N / BN;
    const int bx = blockIdx.x % gn;
    const int by = blockIdx.x / gn;
    const int tid = threadIdx.x;
    const int tx = tid & 15;
    const int ty = tid >> 4;
    const int row0 = by * BM;
    const int col0 = bx * BN;

    float acc[4][4] = {};

    for (int k0 = 0; k0 < K; k0 += BK) {
#pragma unroll
        for (int i = 0; i < 4; ++i) {
            int idx = tid + i * 256;
            int r = idx >> 4, k = idx & 15;
            int gr = row0 + r;
            float v = (gr < M) ? A[(size_t)gr * K + k0 + k] : 0.0f;
            if (RELU_A) v = fmaxf(v, 0.0f);
            As[k][r] = v;
        }
#pragma unroll
        for (int i = 0; i < 4; ++i) {
            int idx = tid + i * 256;
            if (!WT) {
                int k = idx >> 6, n = idx & 63;
                Ws[k][n] = W[(size_t)(k0 + k) * N + col0 + n];
            } else {
                int n = idx >> 4, k = idx & 15;
                Ws[k][n] = W[(size_t)(col0 + n) * K + k0 + k];
            }
        }
        __syncthreads();

#pragma unroll
        for (int kk = 0; kk < BK; ++kk) {
            float a[4], w[4];
#pragma unroll
            for (int i = 0; i < 4; ++i) a[i] = As[kk][ty * 4 + i];
#pragma unroll
            for (int j = 0; j < 4; ++j) w[j] = Ws[kk][tx * 4 + j];
#pragma unroll
            for (int i = 0; i < 4; ++i)
#pragma unroll
                for (int j = 0; j < 4; ++j) acc[i][j] += a[i] * w[j];
        }
        __syncthreads();
    }

#pragma unroll
    for (int i = 0; i < 4; ++i) {
        int gr = row0 + ty * 4 + i;
        if (gr >= M) continue;
#pragma unroll
        for (int j = 0; j < 4; ++j) {
            int gc = col0 + tx * 4 + j;
            float v = acc[i][j];
            if (bias) v += bias[gc];
            C[(size_t)gr * N + gc] = (unsigned short)f2bf(v);
        }
    }
}

// ---------------------------------------------------------------------------
// MFMA pass (64-row tile): A from swizzled LDS (64x128), B fragments straight
// from global (L2-hot weights, [128][128] bf16 k-contiguous). No barriers.
// Wave layout: r0 in {0,32}, c0 in {0,64}; acc[2][4].
// ---------------------------------------------------------------------------
static __device__ __forceinline__ void mfma_pass_g(const short* __restrict__ S,
                                                   const short* __restrict__ Wg,
                                                   int r0, int c0, int lrow, int lk,
                                                   f32x4 acc[2][4]) {
#pragma unroll
    for (int ks = 0; ks < 4; ++ks) {
        int chunk = (ks << 2) + lk;
        bf16x8 a[2], b[4];
#pragma unroll
        for (int m = 0; m < 2; ++m) {
            int rr = r0 + (m << 4) + lrow;
            a[m] = *(const bf16x8*)&S[rr * 128 + ((chunk ^ (rr & 7)) << 3)];
        }
#pragma unroll
        for (int n = 0; n < 4; ++n) {
            int cc = c0 + (n << 4) + lrow;
            b[n] = *(const bf16x8*)&Wg[((size_t)cc << 7) + (chunk << 3)];
        }
#pragma unroll
        for (int m = 0; m < 2; ++m)
#pragma unroll
            for (int n = 0; n < 4; ++n)
                acc[m][n] = __builtin_amdgcn_mfma_f32_16x16x32_bf16(a[m], b[n], acc[m][n], 0, 0, 0);
    }
}

// ---------------------------------------------------------------------------
// bf16 MFMA GEMM (convs): C = relu?(A) @ Wt^T, bf16 out. K=N=128, 64-row tile.
// ---------------------------------------------------------------------------
template <bool RELU_A>
__global__ __launch_bounds__(256, 4) void gemm_mfma_k(const unsigned short* __restrict__ A,
                                                      const short* __restrict__ Wt,
                                                      unsigned short* __restrict__ C,
                                                      int M) {
    __shared__ short As[64 * 128];

    const int row0 = blockIdx.x << 6;
    const int tid = threadIdx.x;

#pragma unroll
    for (int i = 0; i < 4; ++i) {
        int chunk = tid + (i << 8);
        int r = chunk >> 4, c = chunk & 15;
        int gr = row0 + r;
        bf16x8 t;
        if (gr < M) {
            t = *(const bf16x8*)(A + (((size_t)gr) << 7) + (c << 3));
            if (RELU_A) {
#pragma unroll
                for (int j = 0; j < 8; ++j) {
                    unsigned short u = (unsigned short)t[j];
                    t[j] = (short)((u & 0x8000u) ? 0 : u);
                }
            }
        } else {
#pragma unroll
            for (int j = 0; j < 8; ++j) t[j] = 0;
        }
        *(bf16x8*)&As[r * 128 + ((c ^ (r & 7)) << 3)] = t;
    }
    __syncthreads();

    const int lane = tid & 63;
    const int wid = tid >> 6;
    const int r0 = (wid >> 1) << 5;
    const int c0 = (wid & 1) << 6;
    const int lrow = lane & 15;
    const int lk = lane >> 4;

    f32x4 acc[2][4] = {};
    mfma_pass_g(As, Wt, r0, c0, lrow, lk, acc);

    // epilogue: n innermost so the 4 stores covering a 128B line are adjacent
#pragma unroll
    for (int m = 0; m < 2; ++m) {
#pragma unroll
        for (int j = 0; j < 4; ++j) {
            int gr = row0 + r0 + (m << 4) + (lk << 2) + j;
            if (gr >= M) continue;
#pragma unroll
            for (int n = 0; n < 4; ++n) {
                int gc = c0 + (n << 4) + lrow;
                C[((size_t)gr << 7) + gc] = (unsigned short)f2bf(acc[m][n][j]);
            }
        }
    }
}

// ---------------------------------------------------------------------------
// Fused GRU (64-row tile): six gate GEMMs, weights from global (L2),
// A/h tiles in 32KB LDS, ONE barrier, gate math in registers.
// ---------------------------------------------------------------------------
template <bool RELU_A>
__global__ __launch_bounds__(256, 3) void gru_fused_k(const unsigned short* __restrict__ A,
                                                      const unsigned short* __restrict__ hb,
                                                      const short* __restrict__ WihT,
                                                      const short* __restrict__ WhhT,
                                                      const float* __restrict__ bih,
                                                      const float* __restrict__ bhh,
                                                      unsigned short* __restrict__ hnb,
                                                      int M) {
    __shared__ short As[64 * 128];
    __shared__ short Hs[64 * 128];

    const int row0 = blockIdx.x << 6;
    const int tid = threadIdx.x;

    // stage A (relu optional) and h tiles
#pragma unroll
    for (int i = 0; i < 4; ++i) {
        int chunk = tid + (i << 8);
        int r = chunk >> 4, c = chunk & 15;
        int gr = row0 + r;
        bf16x8 ta, th;
        if (gr < M) {
            ta = *(const bf16x8*)(A + (((size_t)gr) << 7) + (c << 3));
            if (RELU_A) {
#pragma unroll
                for (int j = 0; j < 8; ++j) {
                    unsigned short u = (unsigned short)ta[j];
                    ta[j] = (short)((u & 0x8000u) ? 0 : u);
                }
            }
            th = *(const bf16x8*)(hb + (((size_t)gr) << 7) + (c << 3));
        } else {
#pragma unroll
            for (int j = 0; j < 8; ++j) { ta[j] = 0; th[j] = 0; }
        }
        int sw = r * 128 + ((c ^ (r & 7)) << 3);
        *(bf16x8*)&As[sw] = ta;
        *(bf16x8*)&Hs[sw] = th;
    }
    __syncthreads();

    const int lane = tid & 63;
    const int wid = tid >> 6;
    const int r0 = (wid >> 1) << 5;
    const int c0 = (wid & 1) << 6;
    const int lrow = lane & 15;
    const int lk = lane >> 4;

    // biases for this lane's columns
    float br[4], bz[4], bni[4], bnh[4];
#pragma unroll
    for (int n = 0; n < 4; ++n) {
        int gc = c0 + (n << 4) + lrow;
        br[n] = bih[gc] + bhh[gc];
        bz[n] = bih[128 + gc] + bhh[128 + gc];
        bni[n] = bih[256 + gc];
        bnh[n] = bhh[256 + gc];
    }

    const int GS = 128 * 128;  // per-gate weight stride

    f32x4 accR[2][4] = {};
    f32x4 accT[2][4] = {};

    mfma_pass_g(As, WihT, r0, c0, lrow, lk, accR);           // gi_r
    mfma_pass_g(Hs, WhhT, r0, c0, lrow, lk, accR);           // + gh_r
    mfma_pass_g(Hs, WhhT + 2 * GS, r0, c0, lrow, lk, accT);  // gh_n

    // fold: accT = r * (gh_n + bnh)
#pragma unroll
    for (int m = 0; m < 2; ++m)
#pragma unroll
        for (int n = 0; n < 4; ++n)
#pragma unroll
            for (int j = 0; j < 4; ++j) {
                float rr = sigmoidf_(accR[m][n][j] + br[n]);
                accT[m][n][j] = rr * (accT[m][n][j] + bnh[n]);
            }

    mfma_pass_g(As, WihT + 2 * GS, r0, c0, lrow, lk, accT);  // += gi_n

    // n = tanh(accT + bni)
#pragma unroll
    for (int m = 0; m < 2; ++m)
#pragma unroll
        for (int n = 0; n < 4; ++n)
#pragma unroll
            for (int j = 0; j < 4; ++j)
                accT[m][n][j] = tanhf(accT[m][n][j] + bni[n]);

    f32x4 accZ[2][4] = {};
    mfma_pass_g(As, WihT + GS, r0, c0, lrow, lk, accZ);      // gi_z
    mfma_pass_g(Hs, WhhT + GS, r0, c0, lrow, lk, accZ);      // + gh_z

    // epilogue: z, h' = (1-z)*n + z*h ; n innermost for line-local stores
#pragma unroll
    for (int m = 0; m < 2; ++m) {
#pragma unroll
        for (int j = 0; j < 4; ++j) {
            int grow = row0 + r0 + (m << 4) + (lk << 2) + j;
            if (grow >= M) continue;
#pragma unroll
            for (int n = 0; n < 4; ++n) {
                int gcol = c0 + (n << 4) + lrow;
                float zz = sigmoidf_(accZ[m][n][j] + bz[n]);
                float hv = bf2f(hb[((size_t)grow << 7) + gcol]);
                float v = (1.0f - zz) * accT[m][n][j] + zz * hv;
                hnb[((size_t)grow << 7) + gcol] = (unsigned short)f2bf(v);
            }
        }
    }
}

// ---------------------------------------------------------------------------
// GCN gather (pull): one wave per destination node, bf16 HW rows, 4-edge unroll
// out[d] = dd*(dd*HW[d] + sum_e dis[s_e]*HW[s_e]) + bias   (bf16 out)
// ---------------------------------------------------------------------------
__global__ __launch_bounds__(256) void gcn_gather_k(const unsigned short* __restrict__ HW,
                                                    const float* __restrict__ dis,
                                                    const int* __restrict__ rowptr,
                                                    const int* __restrict__ csr_src,
                                                    const float* __restrict__ bias,
                                                    unsigned short* __restrict__ out, int N) {
    int node = (blockIdx.x * 256 + threadIdx.x) >> 6;
    int lane = threadIdx.x & 63;
    if (node >= N) return;
    float dd = dis[node];
    unsigned v0 = *(const unsigned*)&HW[((size_t)node << HBITS) + (lane << 1)];
    float2 b2 = *(const float2*)&bias[lane << 1];
    float accx = bf2f((unsigned short)(v0 & 0xFFFFu)) * dd;
    float accy = bf2f((unsigned short)(v0 >> 16)) * dd;
    int e = rowptr[node], end = rowptr[node + 1];
    for (; e + 3 < end; e += 4) {
        int s0 = csr_src[e], s1 = csr_src[e + 1], s2 = csr_src[e + 2], s3 = csr_src[e + 3];
        float w0 = dis[s0], w1 = dis[s1], w2 = dis[s2], w3 = dis[s3];
        unsigned a = *(const unsigned*)&HW[((size_t)s0 << HBITS) + (lane << 1)];
        unsigned b = *(const unsigned*)&HW[((size_t)s1 << HBITS) + (lane << 1)];
        unsigned c = *(const unsigned*)&HW[((size_t)s2 << HBITS) + (lane << 1)];
        unsigned d = *(const unsigned*)&HW[((size_t)s3 << HBITS) + (lane << 1)];
        accx += bf2f((unsigned short)(a & 0xFFFFu)) * w0;
        accy += bf2f((unsigned short)(a >> 16)) * w0;
        accx += bf2f((unsigned short)(b & 0xFFFFu)) * w1;
        accy += bf2f((unsigned short)(b >> 16)) * w1;
        accx += bf2f((unsigned short)(c & 0xFFFFu)) * w2;
        accy += bf2f((unsigned short)(c >> 16)) * w2;
        accx += bf2f((unsigned short)(d & 0xFFFFu)) * w3;
        accy += bf2f((unsigned short)(d >> 16)) * w3;
    }
    for (; e < end; ++e) {
        int s = csr_src[e];
        float w = dis[s];
        unsigned a = *(const unsigned*)&HW[((size_t)s << HBITS) + (lane << 1)];
        accx += bf2f((unsigned short)(a & 0xFFFFu)) * w;
        accy += bf2f((unsigned short)(a >> 16)) * w;
    }
    accx = accx * dd + b2.x;
    accy = accy * dd + b2.y;
    unsigned o = ((unsigned)(unsigned short)f2bf(accy) << 16) | (unsigned short)f2bf(accx);
    *(unsigned*)&out[((size_t)node << HBITS) + (lane << 1)] = o;
}

// ---------------------------------------------------------------------------
// Output head (bf16 h input)
// ---------------------------------------------------------------------------
#define OUT_DIM 5
__global__ void out_softmax_k(const unsigned short* __restrict__ h,
                              const float* __restrict__ Wo,
                              const float* __restrict__ bo, float* __restrict__ out, int N) {
    int gtid = blockIdx.x * blockDim.x + threadIdx.x;
    int node = gtid >> 6;
    int lane = threadIdx.x & 63;
    if (node >= N) return;
    const unsigned short* hr = h + ((size_t)node << HBITS);
    float h0 = bf2f(hr[lane]);
    float h1 = bf2f(hr[lane + 64]);
    float acc[OUT_DIM];
#pragma unroll
    for (int o = 0; o < OUT_DIM; ++o)
        acc[o] = h0 * Wo[lane * OUT_DIM + o] + h1 * Wo[(lane + 64) * OUT_DIM + o];
#pragma unroll
    for (int off = 32; off >= 1; off >>= 1) {
#pragma unroll
        for (int o = 0; o < OUT_DIM; ++o) acc[o] += __shfl_down(acc[o], off, 64);
    }
    if (lane == 0) {
        float v[OUT_DIM], m = -1e30f;
#pragma unroll
        for (int o = 0; o < OUT_DIM; ++o) { v[o] = acc[o] + bo[o]; m = fmaxf(m, v[o]); }
        float s = 0.0f;
#pragma unroll
        for (int o = 0; o < OUT_DIM; ++o) { v[o] = expf(v[o] - m); s += v[o]; }
        float inv = 1.0f / s;
#pragma unroll
        for (int o = 0; o < OUT_DIM; ++o) out[(size_t)node * OUT_DIM + o] = v[o] * inv;
    }
}

// ---------------------------------------------------------------------------
// launch
// ---------------------------------------------------------------------------
static inline int cdiv(long long a, long long b) { return (int)((a + b - 1) / b); }
static inline char* align256(char* p) {
    return (char*)(((uintptr_t)p + 255) & ~(uintptr_t)255);
}

extern "C" void kernel_launch(void* const* d_in, const int* in_sizes, int n_in,
                              void* d_out, int out_size, void* d_ws, size_t ws_size,
                              hipStream_t stream) {
    const float* x       = (const float*)d_in[0];
    const int*   eidx    = (const int*)d_in[1];
    const float* proj_W  = (const float*)d_in[2];
    const float* proj_b  = (const float*)d_in[3];
    const float* conv1_W = (const float*)d_in[4];
    const float* conv1_b = (const float*)d_in[5];
    const float* conv2_W = (const float*)d_in[6];
    const float* conv2_b = (const float*)d_in[7];
    const float* hidden_c= (const float*)d_in[8];
    const float* gru_Wih = (const float*)d_in[9];
    const float* gru_Whh = (const float*)d_in[10];
    const float* gru_bih = (const float*)d_in[11];
    const float* gru_bhh = (const float*)d_in[12];
    const float* out_W   = (const float*)d_in[13];
    const float* out_b   = (const float*)d_in[14];
    float* out = (float*)d_out;

    const int F = 16, H = 128, G3 = 384;
    const int N = in_sizes[0] / F;
    const int E = in_sizes[1] / 2;
    const int* src = eidx;
    const int* dst = eidx + E;

    const int TPB = 256;
    const int nScanBlocks = cdiv(N, 256);

    // workspace (256B-aligned slots)
    char* wp = (char*)d_ws;
#define ALLOC(ptr_t, name, bytes) ptr_t name = (ptr_t)wp; wp = align256(wp + (bytes))
    ALLOC(int*, cnt, (size_t)N * 4);
    ALLOC(int*, rowptr, (size_t)(N + 1) * 4);
    ALLOC(int*, pos, (size_t)N * 4);
    ALLOC(int*, bsum, 256 * 4);
    ALLOC(int*, csr_src, (size_t)E * 4);
    ALLOC(float*, dis, (size_t)N * 4);
    ALLOC(short*, c1Wt, (size_t)H * H * 2);
    ALLOC(short*, c2Wt, (size_t)H * H * 2);
    ALLOC(short*, WihT, (size_t)G3 * H * 2);
    ALLOC(short*, WhhT, (size_t)G3 * H * 2);
    ALLOC(unsigned short*, h0b, (size_t)N * H * 2);
    ALLOC(unsigned short*, h1b, (size_t)N * H * 2);
    ALLOC(unsigned short*, Abuf, (size_t)N * H * 2);
    ALLOC(unsigned short*, HWb, (size_t)N * H * 2);
#undef ALLOC

    const int totNH = N * H;

    // --- weight preconversion (bf16, [n][k]) ---
    cvt_bf16_t_k<<<cdiv(H * H, TPB), TPB, 0, stream>>>(conv1_W, c1Wt, H, H);
    cvt_bf16_t_k<<<cdiv(H * H, TPB), TPB, 0, stream>>>(conv2_W, c2Wt, H, H);
    cvt_bf16_k<<<cdiv(G3 * H, TPB), TPB, 0, stream>>>(gru_Wih, WihT, G3 * H);
    cvt_bf16_k<<<cdiv(G3 * H, TPB), TPB, 0, stream>>>(gru_Whh, WhhT, G3 * H);

    // --- CSR build + normalization ---
    zero_cnt_k<<<cdiv(N, TPB), TPB, 0, stream>>>(cnt, N);
    count_k<<<cdiv(E, TPB), TPB, 0, stream>>>(dst, cnt, E);
    scan1_k<<<nScanBlocks, 256, 0, stream>>>(cnt, rowptr, bsum, N);
    scan2_k<<<1, 256, 0, stream>>>(bsum, nScanBlocks);
    scan3_k<<<nScanBlocks, 256, 0, stream>>>(rowptr, bsum, cnt, pos, dis, N, E);
    reorder_k<<<cdiv(E, TPB), TPB, 0, stream>>>(src, dst, pos, csr_src, E);

    // --- h init (bf16) ---
    h_init_k<<<cdiv(totNH, TPB), TPB, 0, stream>>>(hidden_c, h0b, totNH);

    unsigned short* hb_cur = h0b;
    unsigned short* hb_nxt = h1b;

    const int gm64 = cdiv(N, 64);
    const int gatherBlocks = cdiv((long long)N * 64, TPB);

    // --- proj (K=16, fp32 path, bf16 out) ---
    dim3 gridP(cdiv(N, BM) * (H / BN));
    gemm_k<false, false><<<gridP, TPB, 0, stream>>>(x, proj_W, proj_b, Abuf, N, F, H);

    // --- GRU step 0 (fused) ---
    gru_fused_k<false><<<gm64, TPB, 0, stream>>>(Abuf, hb_cur, WihT, WhhT,
                                                 gru_bih, gru_bhh, hb_nxt, N);
    { unsigned short* t = hb_cur; hb_cur = hb_nxt; hb_nxt = t; }

    for (int it = 0; it < 3; ++it) {
        gemm_mfma_k<false><<<gm64, TPB, 0, stream>>>(hb_cur, c1Wt, HWb, N);
        gcn_gather_k<<<gatherBlocks, TPB, 0, stream>>>(HWb, dis, rowptr, csr_src,
                                                       conv1_b, Abuf, N);
        gemm_mfma_k<true><<<gm64, TPB, 0, stream>>>(Abuf, c2Wt, HWb, N);
        gcn_gather_k<<<gatherBlocks, TPB, 0, stream>>>(HWb, dis, rowptr, csr_src,
                                                       conv2_b, Abuf, N);
        gru_fused_k<true><<<gm64, TPB, 0, stream>>>(Abuf, hb_cur, WihT, WhhT,
                                                    gru_bih, gru_bhh, hb_nxt, N);
        { unsigned short* t = hb_cur; hb_cur = hb_nxt; hb_nxt = t; }
    }

    // --- output head ---
    out_softmax_k<<<cdiv((long long)N * 64, TPB), TPB, 0, stream>>>(hb_cur, out_W, out_b, out, N);
}

// Round 8
// 644.897 us; speedup vs baseline: 5.5080x; 1.0880x over previous
//
#include <hip/hip_runtime.h>
#include <hip/hip_bf16.h>

#define NODES_H 128
#define HBITS 7   // 128 = 1<<7

typedef __attribute__((ext_vector_type(8))) short bf16x8;
typedef __attribute__((ext_vector_type(4))) float f32x4;

static __device__ __forceinline__ short f2bf(float f) {
    union { float f; unsigned u; } v; v.f = f;
    unsigned r = v.u + 0x7FFFu + ((v.u >> 16) & 1u);  // RNE
    return (short)(r >> 16);
}
static __device__ __forceinline__ float bf2f(unsigned short u) {
    union { unsigned u; float f; } v; v.u = ((unsigned)u) << 16;
    return v.f;
}
// fast sigmoid/tanh via native v_exp_f32 (2^x) + v_rcp_f32 (~1 ulp)
#define LOG2E 1.4426950408889634f
static __device__ __forceinline__ float fast_sigmoid(float x) {
    float t = __builtin_amdgcn_exp2f(-x * LOG2E);
    return __builtin_amdgcn_rcpf(1.0f + t);
}
static __device__ __forceinline__ float fast_tanh(float x) {
    float t = __builtin_amdgcn_exp2f(x * (2.0f * LOG2E));
    return 1.0f - 2.0f * __builtin_amdgcn_rcpf(t + 1.0f);
}

// ---------------------------------------------------------------------------
// weight preconversion
// ---------------------------------------------------------------------------
__global__ void cvt_bf16_k(const float* __restrict__ in, short* __restrict__ out, int n) {
    int i = blockIdx.x * blockDim.x + threadIdx.x;
    if (i < n) out[i] = f2bf(in[i]);
}

__global__ void cvt_bf16_t_k(const float* __restrict__ in, short* __restrict__ out, int K, int N) {
    int i = blockIdx.x * blockDim.x + threadIdx.x;
    if (i >= K * N) return;
    int nn = i >> HBITS;
    int kk = i & (NODES_H - 1);
    out[i] = f2bf(in[kk * N + nn]);  // out[n][k] = in[k][n], K==128
}

// ---------------------------------------------------------------------------
// CSR build
// ---------------------------------------------------------------------------
__global__ void zero_cnt_k(int* __restrict__ cnt, int N) {
    int i = blockIdx.x * blockDim.x + threadIdx.x;
    if (i < N) cnt[i] = 0;
}

__global__ void count_k(const int* __restrict__ dst, int* __restrict__ cnt, int E) {
    int e = blockIdx.x * blockDim.x + threadIdx.x;
    if (e < E) atomicAdd(&cnt[dst[e]], 1);
}

__global__ __launch_bounds__(256) void scan1_k(const int* __restrict__ cnt,
                                               int* __restrict__ rowptr,
                                               int* __restrict__ bsum, int N) {
    __shared__ int buf[256];
    int tid = threadIdx.x;
    int i = blockIdx.x * 256 + tid;
    int v = (i < N) ? cnt[i] : 0;
    buf[tid] = v;
    __syncthreads();
#pragma unroll
    for (int off = 1; off < 256; off <<= 1) {
        int t = (tid >= off) ? buf[tid - off] : 0;
        __syncthreads();
        buf[tid] += t;
        __syncthreads();
    }
    if (i < N) rowptr[i] = buf[tid] - v;
    if (tid == 255) bsum[blockIdx.x] = buf[255];
}

__global__ __launch_bounds__(256) void scan2_k(int* __restrict__ bsum, int nb) {
    __shared__ int buf[256];
    int tid = threadIdx.x;
    int v = (tid < nb) ? bsum[tid] : 0;
    buf[tid] = v;
    __syncthreads();
#pragma unroll
    for (int off = 1; off < 256; off <<= 1) {
        int t = (tid >= off) ? buf[tid - off] : 0;
        __syncthreads();
        buf[tid] += t;
        __syncthreads();
    }
    if (tid < nb) bsum[tid] = buf[tid] - v;
}

__global__ void scan3_k(int* __restrict__ rowptr, const int* __restrict__ bsum,
                        const int* __restrict__ cnt, int* __restrict__ pos,
                        float* __restrict__ dis, int N, int E) {
    int i = blockIdx.x * blockDim.x + threadIdx.x;
    if (i < N) {
        int v = rowptr[i] + bsum[blockIdx.x];
        rowptr[i] = v;
        pos[i] = v;
        dis[i] = rsqrtf((float)(cnt[i] + 1));
    }
    if (i == 0) rowptr[N] = E;
}

__global__ void reorder_k(const int* __restrict__ src, const int* __restrict__ dst,
                          int* __restrict__ pos, int* __restrict__ csr_src, int E) {
    int e = blockIdx.x * blockDim.x + threadIdx.x;
    if (e >= E) return;
    int p = atomicAdd(&pos[dst[e]], 1);
    csr_src[p] = src[e];
}

// ---------------------------------------------------------------------------
// h init (bf16 state only)
// ---------------------------------------------------------------------------
__global__ void h_init_k(const float* __restrict__ hc, unsigned short* __restrict__ hb,
                         int total) {
    int i = blockIdx.x * blockDim.x + threadIdx.x;
    if (i < total) hb[i] = (unsigned short)f2bf(hc[i & (NODES_H - 1)]);
}

// ---------------------------------------------------------------------------
// fp32 tiled GEMM (proj: K=16), bf16 output
// ---------------------------------------------------------------------------
#define BM 64
#define BN 64
#define BK 16

template <bool WT, bool RELU_A>
__global__ __launch_bounds__(256) void gemm_k(const float* __restrict__ A,
                                              const float* __restrict__ W,
                                              const float* __restrict__ bias,
                                              unsigned short* __restrict__ C,
                                              int M, int K, int N) {
    __shared__ float As[BK][BM + 1];
    __shared__ float Ws[BK][BN + 1];

    const int gn = N / BN;
    const int bx = blockIdx.x % gn;
    const int by = blockIdx.x / gn;
    const int tid = threadIdx.x;
    const int tx = tid & 15;
    const int ty = tid >> 4;
    const int row0 = by * BM;
    const int col0 = bx * BN;

    float acc[4][4] = {};

    for (int k0 = 0; k0 < K; k0 += BK) {
#pragma unroll
        for (int i = 0; i < 4; ++i) {
            int idx = tid + i * 256;
            int r = idx >> 4, k = idx & 15;
            int gr = row0 + r;
            float v = (gr < M) ? A[(size_t)gr * K + k0 + k] : 0.0f;
            if (RELU_A) v = fmaxf(v, 0.0f);
            As[k][r] = v;
        }
#pragma unroll
        for (int i = 0; i < 4; ++i) {
            int idx = tid + i * 256;
            if (!WT) {
                int k = idx >> 6, n = idx & 63;
                Ws[k][n] = W[(size_t)(k0 + k) * N + col0 + n];
            } else {
                int n = idx >> 4, k = idx & 15;
                Ws[k][n] = W[(size_t)(col0 + n) * K + k0 + k];
            }
        }
        __syncthreads();

#pragma unroll
        for (int kk = 0; kk < BK; ++kk) {
            float a[4], w[4];
#pragma unroll
            for (int i = 0; i < 4; ++i) a[i] = As[kk][ty * 4 + i];
#pragma unroll
            for (int j = 0; j < 4; ++j) w[j] = Ws[kk][tx * 4 + j];
#pragma unroll
            for (int i = 0; i < 4; ++i)
#pragma unroll
                for (int j = 0; j < 4; ++j) acc[i][j] += a[i] * w[j];
        }
        __syncthreads();
    }

#pragma unroll
    for (int i = 0; i < 4; ++i) {
        int gr = row0 + ty * 4 + i;
        if (gr >= M) continue;
#pragma unroll
        for (int j = 0; j < 4; ++j) {
            int gc = col0 + tx * 4 + j;
            float v = acc[i][j];
            if (bias) v += bias[gc];
            C[(size_t)gr * N + gc] = (unsigned short)f2bf(v);
        }
    }
}

// ---------------------------------------------------------------------------
// MFMA helpers, 64-row tile, wave split m4 x n2 (wave owns 32 cols, all rows).
// B fragments loaded from global weights ([128][128] bf16 k-contiguous) into
// registers; zero cross-wave duplication (4 waves x 32 cols = 128).
// ---------------------------------------------------------------------------
struct BFrags { bf16x8 b[2][4]; };  // [n][ks] — all indices compile-time

static __device__ __forceinline__ void load_b(const short* __restrict__ Wg,
                                              int c0, int lrow, int lk, BFrags& f) {
#pragma unroll
    for (int n = 0; n < 2; ++n) {
        int cc = c0 + (n << 4) + lrow;
#pragma unroll
        for (int ks = 0; ks < 4; ++ks) {
            int chunk = (ks << 2) + lk;
            f.b[n][ks] = *(const bf16x8*)&Wg[((size_t)cc << 7) + (chunk << 3)];
        }
    }
}

static __device__ __forceinline__ void mfma_apply(const short* __restrict__ S,
                                                  const BFrags& f, int lrow, int lk,
                                                  f32x4 acc[4][2]) {
#pragma unroll
    for (int ks = 0; ks < 4; ++ks) {
        int chunk = (ks << 2) + lk;
        bf16x8 a[4];
#pragma unroll
        for (int m = 0; m < 4; ++m) {
            int rr = (m << 4) + lrow;
            a[m] = *(const bf16x8*)&S[rr * 128 + ((chunk ^ (rr & 7)) << 3)];
        }
#pragma unroll
        for (int m = 0; m < 4; ++m)
#pragma unroll
            for (int n = 0; n < 2; ++n)
                acc[m][n] = __builtin_amdgcn_mfma_f32_16x16x32_bf16(a[m], f.b[n][ks], acc[m][n], 0, 0, 0);
    }
}

// swizzled LDS read of one bf16 element (for epilogue h reuse)
static __device__ __forceinline__ float lds_bf16(const short* __restrict__ S, int r, int c) {
    return bf2f((unsigned short)S[r * 128 + (((c >> 3) ^ (r & 7)) << 3) + (c & 7)]);
}

// ---------------------------------------------------------------------------
// bf16 MFMA GEMM (convs): C = relu?(A) @ Wt^T, bf16 out. K=N=128, 64-row tile.
// ---------------------------------------------------------------------------
template <bool RELU_A>
__global__ __launch_bounds__(256, 4) void gemm_mfma_k(const unsigned short* __restrict__ A,
                                                      const short* __restrict__ Wt,
                                                      unsigned short* __restrict__ C,
                                                      int M) {
    __shared__ short As[64 * 128];

    const int row0 = blockIdx.x << 6;
    const int tid = threadIdx.x;

#pragma unroll
    for (int i = 0; i < 4; ++i) {
        int chunk = tid + (i << 8);
        int r = chunk >> 4, c = chunk & 15;
        int gr = row0 + r;
        bf16x8 t;
        if (gr < M) {
            t = *(const bf16x8*)(A + (((size_t)gr) << 7) + (c << 3));
            if (RELU_A) {
#pragma unroll
                for (int j = 0; j < 8; ++j) {
                    unsigned short u = (unsigned short)t[j];
                    t[j] = (short)((u & 0x8000u) ? 0 : u);
                }
            }
        } else {
#pragma unroll
            for (int j = 0; j < 8; ++j) t[j] = 0;
        }
        *(bf16x8*)&As[r * 128 + ((c ^ (r & 7)) << 3)] = t;
    }

    const int lane = tid & 63;
    const int wid = tid >> 6;
    const int c0 = wid << 5;
    const int lrow = lane & 15;
    const int lk = lane >> 4;

    BFrags bf;
    load_b(Wt, c0, lrow, lk, bf);  // overlap with staging
    __syncthreads();

    f32x4 acc[4][2] = {};
    mfma_apply(As, bf, lrow, lk, acc);

#pragma unroll
    for (int m = 0; m < 4; ++m) {
#pragma unroll
        for (int j = 0; j < 4; ++j) {
            int gr = row0 + (m << 4) + (lk << 2) + j;
            if (gr >= M) continue;
#pragma unroll
            for (int n = 0; n < 2; ++n) {
                int gc = c0 + (n << 4) + lrow;
                C[((size_t)gr << 7) + gc] = (unsigned short)f2bf(acc[m][n][j]);
            }
        }
    }
}

// ---------------------------------------------------------------------------
// Fused GRU (64-row tile): six gate GEMM passes, weights from global (L2),
// A/h tiles in 32KB LDS, one barrier, FAST gate math (native exp2/rcp).
// ---------------------------------------------------------------------------
template <bool RELU_A>
__global__ __launch_bounds__(256, 3) void gru_fused_k(const unsigned short* __restrict__ A,
                                                      const unsigned short* __restrict__ hb,
                                                      const short* __restrict__ WihT,
                                                      const short* __restrict__ WhhT,
                                                      const float* __restrict__ bih,
                                                      const float* __restrict__ bhh,
                                                      unsigned short* __restrict__ hnb,
                                                      int M) {
    __shared__ short As[64 * 128];
    __shared__ short Hs[64 * 128];

    const int row0 = blockIdx.x << 6;
    const int tid = threadIdx.x;

    // stage A (relu optional) and h tiles
#pragma unroll
    for (int i = 0; i < 4; ++i) {
        int chunk = tid + (i << 8);
        int r = chunk >> 4, c = chunk & 15;
        int gr = row0 + r;
        bf16x8 ta, th;
        if (gr < M) {
            ta = *(const bf16x8*)(A + (((size_t)gr) << 7) + (c << 3));
            if (RELU_A) {
#pragma unroll
                for (int j = 0; j < 8; ++j) {
                    unsigned short u = (unsigned short)ta[j];
                    ta[j] = (short)((u & 0x8000u) ? 0 : u);
                }
            }
            th = *(const bf16x8*)(hb + (((size_t)gr) << 7) + (c << 3));
        } else {
#pragma unroll
            for (int j = 0; j < 8; ++j) { ta[j] = 0; th[j] = 0; }
        }
        int sw = r * 128 + ((c ^ (r & 7)) << 3);
        *(bf16x8*)&As[sw] = ta;
        *(bf16x8*)&Hs[sw] = th;
    }

    const int lane = tid & 63;
    const int wid = tid >> 6;
    const int c0 = wid << 5;
    const int lrow = lane & 15;
    const int lk = lane >> 4;

    // biases for this lane's columns
    float br[2], bz[2], bni[2], bnh[2];
#pragma unroll
    for (int n = 0; n < 2; ++n) {
        int gc = c0 + (n << 4) + lrow;
        br[n] = bih[gc] + bhh[gc];
        bz[n] = bih[128 + gc] + bhh[128 + gc];
        bni[n] = bih[256 + gc];
        bnh[n] = bhh[256 + gc];
    }

    const int GS = 128 * 128;  // per-gate weight stride
    BFrags bf;
    load_b(WihT, c0, lrow, lk, bf);  // overlap first B with staging
    __syncthreads();

    f32x4 accR[4][2] = {};
    f32x4 accT[4][2] = {};

    mfma_apply(As, bf, lrow, lk, accR);            // gi_r
    load_b(WhhT, c0, lrow, lk, bf);
    mfma_apply(Hs, bf, lrow, lk, accR);            // + gh_r
    load_b(WhhT + 2 * GS, c0, lrow, lk, bf);
    mfma_apply(Hs, bf, lrow, lk, accT);            // gh_n

    // fold: accT = r * (gh_n + bnh)
#pragma unroll
    for (int m = 0; m < 4; ++m)
#pragma unroll
        for (int n = 0; n < 2; ++n)
#pragma unroll
            for (int j = 0; j < 4; ++j) {
                float rr = fast_sigmoid(accR[m][n][j] + br[n]);
                accT[m][n][j] = rr * (accT[m][n][j] + bnh[n]);
            }

    load_b(WihT + 2 * GS, c0, lrow, lk, bf);
    mfma_apply(As, bf, lrow, lk, accT);            // += gi_n

    // n = tanh(accT + bni)
#pragma unroll
    for (int m = 0; m < 4; ++m)
#pragma unroll
        for (int n = 0; n < 2; ++n)
#pragma unroll
            for (int j = 0; j < 4; ++j)
                accT[m][n][j] = fast_tanh(accT[m][n][j] + bni[n]);

    f32x4 accZ[4][2] = {};
    load_b(WihT + GS, c0, lrow, lk, bf);
    mfma_apply(As, bf, lrow, lk, accZ);            // gi_z
    load_b(WhhT + GS, c0, lrow, lk, bf);
    mfma_apply(Hs, bf, lrow, lk, accZ);            // + gh_z

    // epilogue: z, h' = (1-z)*n + z*h ; h read from staged LDS tile
#pragma unroll
    for (int m = 0; m < 4; ++m) {
#pragma unroll
        for (int j = 0; j < 4; ++j) {
            int lr = (m << 4) + (lk << 2) + j;
            int grow = row0 + lr;
            if (grow >= M) continue;
#pragma unroll
            for (int n = 0; n < 2; ++n) {
                int gcol = c0 + (n << 4) + lrow;
                float zz = fast_sigmoid(accZ[m][n][j] + bz[n]);
                float hv = lds_bf16(Hs, lr, gcol);
                float v = (1.0f - zz) * accT[m][n][j] + zz * hv;
                hnb[((size_t)grow << 7) + gcol] = (unsigned short)f2bf(v);
            }
        }
    }
}

// ---------------------------------------------------------------------------
// GCN gather (pull): one wave per destination node, bf16 HW rows, 4-edge unroll
// ---------------------------------------------------------------------------
__global__ __launch_bounds__(256) void gcn_gather_k(const unsigned short* __restrict__ HW,
                                                    const float* __restrict__ dis,
                                                    const int* __restrict__ rowptr,
                                                    const int* __restrict__ csr_src,
                                                    const float* __restrict__ bias,
                                                    unsigned short* __restrict__ out, int N) {
    int node = (blockIdx.x * 256 + threadIdx.x) >> 6;
    int lane = threadIdx.x & 63;
    if (node >= N) return;
    float dd = dis[node];
    unsigned v0 = *(const unsigned*)&HW[((size_t)node << HBITS) + (lane << 1)];
    float2 b2 = *(const float2*)&bias[lane << 1];
    float accx = bf2f((unsigned short)(v0 & 0xFFFFu)) * dd;
    float accy = bf2f((unsigned short)(v0 >> 16)) * dd;
    int e = rowptr[node], end = rowptr[node + 1];
    for (; e + 3 < end; e += 4) {
        int s0 = csr_src[e], s1 = csr_src[e + 1], s2 = csr_src[e + 2], s3 = csr_src[e + 3];
        float w0 = dis[s0], w1 = dis[s1], w2 = dis[s2], w3 = dis[s3];
        unsigned a = *(const unsigned*)&HW[((size_t)s0 << HBITS) + (lane << 1)];
        unsigned b = *(const unsigned*)&HW[((size_t)s1 << HBITS) + (lane << 1)];
        unsigned c = *(const unsigned*)&HW[((size_t)s2 << HBITS) + (lane << 1)];
        unsigned d = *(const unsigned*)&HW[((size_t)s3 << HBITS) + (lane << 1)];
        accx += bf2f((unsigned short)(a & 0xFFFFu)) * w0;
        accy += bf2f((unsigned short)(a >> 16)) * w0;
        accx += bf2f((unsigned short)(b & 0xFFFFu)) * w1;
        accy += bf2f((unsigned short)(b >> 16)) * w1;
        accx += bf2f((unsigned short)(c & 0xFFFFu)) * w2;
        accy += bf2f((unsigned short)(c >> 16)) * w2;
        accx += bf2f((unsigned short)(d & 0xFFFFu)) * w3;
        accy += bf2f((unsigned short)(d >> 16)) * w3;
    }
    for (; e < end; ++e) {
        int s = csr_src[e];
        float w = dis[s];
        unsigned a = *(const unsigned*)&HW[((size_t)s << HBITS) + (lane << 1)];
        accx += bf2f((unsigned short)(a & 0xFFFFu)) * w;
        accy += bf2f((unsigned short)(a >> 16)) * w;
    }
    accx = accx * dd + b2.x;
    accy = accy * dd + b2.y;
    unsigned o = ((unsigned)(unsigned short)f2bf(accy) << 16) | (unsigned short)f2bf(accx);
    *(unsigned*)&out[((size_t)node << HBITS) + (lane << 1)] = o;
}

// ---------------------------------------------------------------------------
// Output head (bf16 h input)
// ---------------------------------------------------------------------------
#define OUT_DIM 5
__global__ void out_softmax_k(const unsigned short* __restrict__ h,
                              const float* __restrict__ Wo,
                              const float* __restrict__ bo, float* __restrict__ out, int N) {
    int gtid = blockIdx.x * blockDim.x + threadIdx.x;
    int node = gtid >> 6;
    int lane = threadIdx.x & 63;
    if (node >= N) return;
    const unsigned short* hr = h + ((size_t)node << HBITS);
    float h0 = bf2f(hr[lane]);
    float h1 = bf2f(hr[lane + 64]);
    float acc[OUT_DIM];
#pragma unroll
    for (int o = 0; o < OUT_DIM; ++o)
        acc[o] = h0 * Wo[lane * OUT_DIM + o] + h1 * Wo[(lane + 64) * OUT_DIM + o];
#pragma unroll
    for (int off = 32; off >= 1; off >>= 1) {
#pragma unroll
        for (int o = 0; o < OUT_DIM; ++o) acc[o] += __shfl_down(acc[o], off, 64);
    }
    if (lane == 0) {
        float v[OUT_DIM], m = -1e30f;
#pragma unroll
        for (int o = 0; o < OUT_DIM; ++o) { v[o] = acc[o] + bo[o]; m = fmaxf(m, v[o]); }
        float s = 0.0f;
#pragma unroll
        for (int o = 0; o < OUT_DIM; ++o) { v[o] = __builtin_amdgcn_exp2f((v[o] - m) * LOG2E); s += v[o]; }
        float inv = 1.0f / s;
#pragma unroll
        for (int o = 0; o < OUT_DIM; ++o) out[(size_t)node * OUT_DIM + o] = v[o] * inv;
    }
}

// ---------------------------------------------------------------------------
// launch
// ---------------------------------------------------------------------------
static inline int cdiv(long long a, long long b) { return (int)((a + b - 1) / b); }
static inline char* align256(char* p) {
    return (char*)(((uintptr_t)p + 255) & ~(uintptr_t)255);
}

extern "C" void kernel_launch(void* const* d_in, const int* in_sizes, int n_in,
                              void* d_out, int out_size, void* d_ws, size_t ws_size,
                              hipStream_t stream) {
    const float* x       = (const float*)d_in[0];
    const int*   eidx    = (const int*)d_in[1];
    const float* proj_W  = (const float*)d_in[2];
    const float* proj_b  = (const float*)d_in[3];
    const float* conv1_W = (const float*)d_in[4];
    const float* conv1_b = (const float*)d_in[5];
    const float* conv2_W = (const float*)d_in[6];
    const float* conv2_b = (const float*)d_in[7];
    const float* hidden_c= (const float*)d_in[8];
    const float* gru_Wih = (const float*)d_in[9];
    const float* gru_Whh = (const float*)d_in[10];
    const float* gru_bih = (const float*)d_in[11];
    const float* gru_bhh = (const float*)d_in[12];
    const float* out_W   = (const float*)d_in[13];
    const float* out_b   = (const float*)d_in[14];
    float* out = (float*)d_out;

    const int F = 16, H = 128, G3 = 384;
    const int N = in_sizes[0] / F;
    const int E = in_sizes[1] / 2;
    const int* src = eidx;
    const int* dst = eidx + E;

    const int TPB = 256;
    const int nScanBlocks = cdiv(N, 256);

    // workspace (256B-aligned slots)
    char* wp = (char*)d_ws;
#define ALLOC(ptr_t, name, bytes) ptr_t name = (ptr_t)wp; wp = align256(wp + (bytes))
    ALLOC(int*, cnt, (size_t)N * 4);
    ALLOC(int*, rowptr, (size_t)(N + 1) * 4);
    ALLOC(int*, pos, (size_t)N * 4);
    ALLOC(int*, bsum, 256 * 4);
    ALLOC(int*, csr_src, (size_t)E * 4);
    ALLOC(float*, dis, (size_t)N * 4);
    ALLOC(short*, c1Wt, (size_t)H * H * 2);
    ALLOC(short*, c2Wt, (size_t)H * H * 2);
    ALLOC(short*, WihT, (size_t)G3 * H * 2);
    ALLOC(short*, WhhT, (size_t)G3 * H * 2);
    ALLOC(unsigned short*, h0b, (size_t)N * H * 2);
    ALLOC(unsigned short*, h1b, (size_t)N * H * 2);
    ALLOC(unsigned short*, Abuf, (size_t)N * H * 2);
    ALLOC(unsigned short*, HWb, (size_t)N * H * 2);
#undef ALLOC

    const int totNH = N * H;

    // --- weight preconversion (bf16, [n][k]) ---
    cvt_bf16_t_k<<<cdiv(H * H, TPB), TPB, 0, stream>>>(conv1_W, c1Wt, H, H);
    cvt_bf16_t_k<<<cdiv(H * H, TPB), TPB, 0, stream>>>(conv2_W, c2Wt, H, H);
    cvt_bf16_k<<<cdiv(G3 * H, TPB), TPB, 0, stream>>>(gru_Wih, WihT, G3 * H);
    cvt_bf16_k<<<cdiv(G3 * H, TPB), TPB, 0, stream>>>(gru_Whh, WhhT, G3 * H);

    // --- CSR build + normalization ---
    zero_cnt_k<<<cdiv(N, TPB), TPB, 0, stream>>>(cnt, N);
    count_k<<<cdiv(E, TPB), TPB, 0, stream>>>(dst, cnt, E);
    scan1_k<<<nScanBlocks, 256, 0, stream>>>(cnt, rowptr, bsum, N);
    scan2_k<<<1, 256, 0, stream>>>(bsum, nScanBlocks);
    scan3_k<<<nScanBlocks, 256, 0, stream>>>(rowptr, bsum, cnt, pos, dis, N, E);
    reorder_k<<<cdiv(E, TPB), TPB, 0, stream>>>(src, dst, pos, csr_src, E);

    // --- h init (bf16) ---
    h_init_k<<<cdiv(totNH, TPB), TPB, 0, stream>>>(hidden_c, h0b, totNH);

    unsigned short* hb_cur = h0b;
    unsigned short* hb_nxt = h1b;

    const int gm64 = cdiv(N, 64);
    const int gatherBlocks = cdiv((long long)N * 64, TPB);

    // --- proj (K=16, fp32 path, bf16 out) ---
    dim3 gridP(cdiv(N, BM) * (H / BN));
    gemm_k<false, false><<<gridP, TPB, 0, stream>>>(x, proj_W, proj_b, Abuf, N, F, H);

    // --- GRU step 0 (fused) ---
    gru_fused_k<false><<<gm64, TPB, 0, stream>>>(Abuf, hb_cur, WihT, WhhT,
                                                 gru_bih, gru_bhh, hb_nxt, N);
    { unsigned short* t = hb_cur; hb_cur = hb_nxt; hb_nxt = t; }

    for (int it = 0; it < 3; ++it) {
        gemm_mfma_k<false><<<gm64, TPB, 0, stream>>>(hb_cur, c1Wt, HWb, N);
        gcn_gather_k<<<gatherBlocks, TPB, 0, stream>>>(HWb, dis, rowptr, csr_src,
                                                       conv1_b, Abuf, N);
        gemm_mfma_k<true><<<gm64, TPB, 0, stream>>>(Abuf, c2Wt, HWb, N);
        gcn_gather_k<<<gatherBlocks, TPB, 0, stream>>>(HWb, dis, rowptr, csr_src,
                                                       conv2_b, Abuf, N);
        gru_fused_k<true><<<gm64, TPB, 0, stream>>>(Abuf, hb_cur, WihT, WhhT,
                                                    gru_bih, gru_bhh, hb_nxt, N);
        { unsigned short* t = hb_cur; hb_cur = hb_nxt; hb_nxt = t; }
    }

    // --- output head ---
    out_softmax_k<<<cdiv((long long)N * 64, TPB), TPB, 0, stream>>>(hb_cur, out_W, out_b, out, N);
}